// Round 1
// baseline (1760.305 us; speedup 1.0000x reference)
//
#include <hip/hip_runtime.h>
#include <hip/hip_bf16.h>

typedef __bf16 bf16_t;
typedef bf16_t bf16x8 __attribute__((ext_vector_type(8)));
typedef float f32x4 __attribute__((ext_vector_type(4)));

#define MFMA16(a, b, c) __builtin_amdgcn_mfma_f32_16x16x32_bf16(a, b, c, 0, 0, 0)
#define NEGV -1e30f

__device__ __forceinline__ unsigned short f2bf(float f) {
  union { float f; unsigned int u; } v; v.f = f;
  unsigned int r = v.u + 0x7FFFu + ((v.u >> 16) & 1u);
  return (unsigned short)(r >> 16);
}

// ---------------- Kernel A: QKV projection ----------------
// Out[b,h,l,d] = sum_d' x[b,d',l] * w[h*128+d, d'] + bias   (bf16)
// z==2 (V) stored transposed: Vt[b,h,d,l]
__global__ __launch_bounds__(256) void qkv_proj(
    const float* __restrict__ x,
    const float* __restrict__ wq, const float* __restrict__ wk, const float* __restrict__ wv,
    const float* __restrict__ bq, const float* __restrict__ bk, const float* __restrict__ bv,
    unsigned short* __restrict__ Q, unsigned short* __restrict__ K, unsigned short* __restrict__ Vt)
{
  const int tid = threadIdx.x;
  const int wave = tid >> 6, lane = tid & 63;
  const int lr = lane & 15, lg = lane >> 4;
  const int wr = wave >> 1, wc = wave & 1;
  const int mt = blockIdx.x & 7, nt = blockIdx.x >> 3;
  const int b = blockIdx.y, z = blockIdx.z;
  const int l0 = mt * 128, i0 = nt * 128;
  const float* w    = (z == 0) ? wq : (z == 1) ? wk : wv;
  const float* bias = (z == 0) ? bq : (z == 1) ? bk : bv;
  unsigned short* outp = (z == 0) ? Q : (z == 1) ? K : Vt;

  __shared__ __align__(16) unsigned short lA[128 * 40];  // [l][d] transposed x tile, pad 40
  __shared__ __align__(16) unsigned short lB[128 * 40];  // [i][d] weight tile

  f32x4 acc[4][4];
#pragma unroll
  for (int m = 0; m < 4; ++m)
#pragma unroll
    for (int n = 0; n < 4; ++n) acc[m][n] = (f32x4){0.f, 0.f, 0.f, 0.f};

  const int ad = tid >> 3, aj = tid & 7;  // x staging: row d, col-group
  const int br = tid >> 1, bh2 = tid & 1; // w staging: row i, half

  for (int k0 = 0; k0 < 1024; k0 += 32) {
    // stage x[d0:d0+32][l0:l0+128] transposed -> lA[l][d] (bf16)
    const float* xp = x + ((size_t)b * 1024 + k0 + ad) * 1024 + l0;
#pragma unroll
    for (int rep = 0; rep < 4; ++rep) {
      float4 v = *reinterpret_cast<const float4*>(xp + aj * 4 + rep * 32);
      int lb = aj * 4 + rep * 32;
      lA[(lb + 0) * 40 + ad] = f2bf(v.x);
      lA[(lb + 1) * 40 + ad] = f2bf(v.y);
      lA[(lb + 2) * 40 + ad] = f2bf(v.z);
      lA[(lb + 3) * 40 + ad] = f2bf(v.w);
    }
    // stage w[i0:i0+128][k0:k0+32] -> lB[i][d] (bf16)
    const float* wp = w + (size_t)(i0 + br) * 1024 + k0 + bh2 * 16;
#pragma unroll
    for (int rep = 0; rep < 4; ++rep) {
      float4 v = *reinterpret_cast<const float4*>(wp + rep * 4);
      int cb = br * 40 + bh2 * 16 + rep * 4;
      lB[cb + 0] = f2bf(v.x); lB[cb + 1] = f2bf(v.y);
      lB[cb + 2] = f2bf(v.z); lB[cb + 3] = f2bf(v.w);
    }
    __syncthreads();
    bf16x8 af[4], bfr[4];
#pragma unroll
    for (int m = 0; m < 4; ++m)
      af[m] = *reinterpret_cast<const bf16x8*>(&lA[(wr * 64 + m * 16 + lr) * 40 + lg * 8]);
#pragma unroll
    for (int n = 0; n < 4; ++n)
      bfr[n] = *reinterpret_cast<const bf16x8*>(&lB[(wc * 64 + n * 16 + lr) * 40 + lg * 8]);
#pragma unroll
    for (int m = 0; m < 4; ++m)
#pragma unroll
      for (int n = 0; n < 4; ++n)
        acc[m][n] = MFMA16(af[m], bfr[n], acc[m][n]);
    __syncthreads();
  }
  // epilogue: C[row=l][col=i]; col=lane&15, row=(lane>>4)*4+ii
#pragma unroll
  for (int n = 0; n < 4; ++n) {
    int col = i0 + wc * 64 + n * 16 + lr;
    float bs = bias[col];
    int h = col >> 7, d = col & 127;
#pragma unroll
    for (int m = 0; m < 4; ++m) {
#pragma unroll
      for (int ii = 0; ii < 4; ++ii) {
        int row = l0 + wr * 64 + m * 16 + lg * 4 + ii;
        unsigned short val = f2bf(acc[m][n][ii] + bs);
        if (z < 2)
          outp[(((size_t)b * 8 + h) * 1024 + row) * 128 + d] = val;
        else
          outp[(((size_t)b * 8 + h) * 128 + d) * 1024 + row] = val;
      }
    }
  }
}

// ---------------- Kernel B: flash attention ----------------
// grid (16 qtiles, 8 heads, 32 batch); 256 thr = 4 waves, 16 q-rows each.
__global__ __launch_bounds__(256) void flash_attn(
    const unsigned short* Q, const unsigned short* Kb, const unsigned short* Vt,
    const int* __restrict__ mask, unsigned short* O)
{
  const int tid = threadIdx.x, wave = tid >> 6, lane = tid & 63;
  const int lr = lane & 15, lg = lane >> 4;
  const int qt = blockIdx.x, h = blockIdx.y, b = blockIdx.z;
  const size_t bh = (size_t)b * 8 + h;
  const unsigned short* Qp = Q + bh * 131072;
  const unsigned short* Kp = Kb + bh * 131072;
  const unsigned short* Vp = Vt + bh * 131072;
  unsigned short* Op = O + bh * 131072;
  const int* mp = mask + b * 1024;
  const int q0 = qt * 64 + wave * 16;
  const float SC = 0.08838834764831845f;  // 1/sqrt(128)

  __shared__ __align__(16) unsigned short plds[4][16 * 72];
  unsigned short* myP = plds[wave];

  bf16x8 aq[4];
#pragma unroll
  for (int c = 0; c < 4; ++c)
    aq[c] = *reinterpret_cast<const bf16x8*>(&Qp[(size_t)(q0 + lr) * 128 + c * 32 + lg * 8]);

  f32x4 oacc[8];
#pragma unroll
  for (int dt = 0; dt < 8; ++dt) oacc[dt] = (f32x4){0.f, 0.f, 0.f, 0.f};
  float mrun[4] = {NEGV, NEGV, NEGV, NEGV};
  float lrun[4] = {0.f, 0.f, 0.f, 0.f};

  for (int kt = 0; kt < 1024; kt += 64) {
    // S = Q K^T  (4 col-tiles of 16 keys)
    f32x4 s[4];
#pragma unroll
    for (int n = 0; n < 4; ++n) {
      f32x4 a = (f32x4){0.f, 0.f, 0.f, 0.f};
#pragma unroll
      for (int c = 0; c < 4; ++c) {
        bf16x8 bk = *reinterpret_cast<const bf16x8*>(
            &Kp[(size_t)(kt + n * 16 + lr) * 128 + c * 32 + lg * 8]);
        a = MFMA16(aq[c], bk, a);
      }
      s[n] = a;
    }
    // scale + mask (col = lane&15 within tile n)
#pragma unroll
    for (int n = 0; n < 4; ++n) {
      bool msk = mp[kt + n * 16 + lr] != 0;
#pragma unroll
      for (int i = 0; i < 4; ++i)
        s[n][i] = msk ? NEGV : s[n][i] * SC;
    }
    // online softmax: row i lives across the 16 lanes of each lane-group
    float p[4][4];
#pragma unroll
    for (int i = 0; i < 4; ++i) {
      float mx = fmaxf(fmaxf(s[0][i], s[1][i]), fmaxf(s[2][i], s[3][i]));
      mx = fmaxf(mx, __shfl_xor(mx, 1));
      mx = fmaxf(mx, __shfl_xor(mx, 2));
      mx = fmaxf(mx, __shfl_xor(mx, 4));
      mx = fmaxf(mx, __shfl_xor(mx, 8));
      float mnew = fmaxf(mrun[i], mx);
      float sc = __expf(mrun[i] - mnew);
      mrun[i] = mnew;
      float ps = 0.f;
#pragma unroll
      for (int n = 0; n < 4; ++n) {
        float pv = __expf(s[n][i] - mnew);
        p[n][i] = pv;
        ps += pv;
      }
      ps += __shfl_xor(ps, 1); ps += __shfl_xor(ps, 2);
      ps += __shfl_xor(ps, 4); ps += __shfl_xor(ps, 8);
      lrun[i] = lrun[i] * sc + ps;
#pragma unroll
      for (int dt = 0; dt < 8; ++dt) oacc[dt][i] *= sc;
    }
    // P (D-layout) -> per-wave LDS -> A-frag layout
#pragma unroll
    for (int n = 0; n < 4; ++n)
#pragma unroll
      for (int i = 0; i < 4; ++i)
        myP[(lg * 4 + i) * 72 + n * 16 + lr] = f2bf(p[n][i]);
    __syncthreads();
    bf16x8 pa[2];
    pa[0] = *reinterpret_cast<const bf16x8*>(&myP[lr * 72 + lg * 8]);
    pa[1] = *reinterpret_cast<const bf16x8*>(&myP[lr * 72 + 32 + lg * 8]);
    // O += P V   (V^T stored [d][l] -> gemm_bt, k-contiguous)
#pragma unroll
    for (int dt = 0; dt < 8; ++dt) {
#pragma unroll
      for (int ks = 0; ks < 2; ++ks) {
        bf16x8 bv = *reinterpret_cast<const bf16x8*>(
            &Vp[(size_t)(dt * 16 + lr) * 1024 + kt + ks * 32 + lg * 8]);
        oacc[dt] = MFMA16(pa[ks], bv, oacc[dt]);
      }
    }
    __syncthreads();
  }
  float inv[4];
#pragma unroll
  for (int i = 0; i < 4; ++i) inv[i] = 1.f / lrun[i];
#pragma unroll
  for (int dt = 0; dt < 8; ++dt)
#pragma unroll
    for (int i = 0; i < 4; ++i)
      Op[(size_t)(q0 + lg * 4 + i) * 128 + dt * 16 + lr] = f2bf(oacc[dt][i] * inv[i]);
}

// ---------------- Kernel C: output projection ----------------
// out[b,d,l] = sum_j O[b,l,j] * wo[d,j] + bo[d]   (fp32 out, [B,D,L])
__global__ __launch_bounds__(256) void out_proj(
    const unsigned short* __restrict__ Obuf, const float* __restrict__ wo,
    const float* __restrict__ bo, float* __restrict__ out)
{
  const int tid = threadIdx.x, wave = tid >> 6, lane = tid & 63;
  const int lr = lane & 15, lg = lane >> 4;
  const int wr = wave >> 1, wc = wave & 1;
  const int mt = blockIdx.x & 7, nt = blockIdx.x >> 3;
  const int b = blockIdx.y;
  const int d0 = mt * 128, l0 = nt * 128;

  __shared__ __align__(16) unsigned short lA[128 * 40];  // wo rows (d_out)
  __shared__ __align__(16) unsigned short lB[128 * 40];  // O rows (l)

  f32x4 acc[4][4];
#pragma unroll
  for (int m = 0; m < 4; ++m)
#pragma unroll
    for (int n = 0; n < 4; ++n) acc[m][n] = (f32x4){0.f, 0.f, 0.f, 0.f};

  const int ar = tid >> 1, ah = tid & 1;

  for (int k0 = 0; k0 < 1024; k0 += 32) {
    const float* wp = wo + (size_t)(d0 + ar) * 1024 + k0 + ah * 16;
#pragma unroll
    for (int rep = 0; rep < 4; ++rep) {
      float4 v = *reinterpret_cast<const float4*>(wp + rep * 4);
      int cb = ar * 40 + ah * 16 + rep * 4;
      lA[cb + 0] = f2bf(v.x); lA[cb + 1] = f2bf(v.y);
      lA[cb + 2] = f2bf(v.z); lA[cb + 3] = f2bf(v.w);
    }
    {
      int head = k0 >> 7, dk = (k0 & 127) + ah * 16;
      const unsigned short* op =
          Obuf + (((size_t)b * 8 + head) * 1024 + l0 + ar) * 128 + dk;
#pragma unroll
      for (int rep = 0; rep < 2; ++rep) {
        bf16x8 v = *reinterpret_cast<const bf16x8*>(op + rep * 8);
        *reinterpret_cast<bf16x8*>(&lB[ar * 40 + ah * 16 + rep * 8]) = v;
      }
    }
    __syncthreads();
    bf16x8 af[4], bfr[4];
#pragma unroll
    for (int m = 0; m < 4; ++m)
      af[m] = *reinterpret_cast<const bf16x8*>(&lA[(wr * 64 + m * 16 + lr) * 40 + lg * 8]);
#pragma unroll
    for (int n = 0; n < 4; ++n)
      bfr[n] = *reinterpret_cast<const bf16x8*>(&lB[(wc * 64 + n * 16 + lr) * 40 + lg * 8]);
#pragma unroll
    for (int m = 0; m < 4; ++m)
#pragma unroll
      for (int n = 0; n < 4; ++n)
        acc[m][n] = MFMA16(af[m], bfr[n], acc[m][n]);
    __syncthreads();
  }
  // epilogue: rows = d_out, cols = l -> coalesced stores into [B,D,L]
#pragma unroll
  for (int m = 0; m < 4; ++m) {
#pragma unroll
    for (int ii = 0; ii < 4; ++ii) {
      int dr = d0 + wr * 64 + m * 16 + lg * 4 + ii;
      float bs = bo[dr];
      float* orow = out + ((size_t)b * 1024 + dr) * 1024 + l0 + wc * 64 + lr;
#pragma unroll
      for (int n = 0; n < 4; ++n)
        orow[n * 16] = acc[m][n][ii] + bs;
    }
  }
}

extern "C" void kernel_launch(void* const* d_in, const int* in_sizes, int n_in,
                              void* d_out, int out_size, void* d_ws, size_t ws_size,
                              hipStream_t stream) {
  const float* x  = (const float*)d_in[0];
  const int* mask = (const int*)d_in[1];
  const float* wq = (const float*)d_in[2];
  const float* bq = (const float*)d_in[3];
  const float* wk = (const float*)d_in[4];
  const float* bk = (const float*)d_in[5];
  const float* wv = (const float*)d_in[6];
  const float* bv = (const float*)d_in[7];
  const float* wo = (const float*)d_in[8];
  const float* bo = (const float*)d_in[9];
  float* out = (float*)d_out;

  unsigned short* Q  = (unsigned short*)d_ws;          // [32][8][1024][128] bf16, later O
  unsigned short* K  = Q + (size_t)33554432;           // 64 MiB each
  unsigned short* Vt = K + (size_t)33554432;           // V transposed [32][8][128][1024]

  qkv_proj<<<dim3(64, 32, 3), 256, 0, stream>>>(x, wq, wk, wv, bq, bk, bv, Q, K, Vt);
  flash_attn<<<dim3(16, 8, 32), 256, 0, stream>>>(Q, K, Vt, mask, Q /* O aliases Q */);
  out_proj<<<dim3(64, 32), 256, 0, stream>>>(Q, wo, bo, out);
}

// Round 2
// 997.933 us; speedup vs baseline: 1.7640x; 1.7640x over previous
//
#include <hip/hip_runtime.h>
#include <hip/hip_bf16.h>

typedef __bf16 bf16_t;
typedef bf16_t bf16x8 __attribute__((ext_vector_type(8)));
typedef float f32x4 __attribute__((ext_vector_type(4)));

#define MFMA16(a, b, c) __builtin_amdgcn_mfma_f32_16x16x32_bf16(a, b, c, 0, 0, 0)
#define NEGV -1e30f

__device__ __forceinline__ unsigned short f2bf(float f) {
  union { float f; unsigned int u; } v; v.f = f;
  unsigned int r = v.u + 0x7FFFu + ((v.u >> 16) & 1u);
  return (unsigned short)(r >> 16);
}

__device__ __forceinline__ void gload16(const unsigned short* g, unsigned short* l) {
  __builtin_amdgcn_global_load_lds(
      (const __attribute__((address_space(1))) void*)g,
      (__attribute__((address_space(3))) void*)l, 16, 0, 0);
}

// ---------------- Kernel A: QKV projection ----------------
// Out[b,h,l,d] = sum_d' x[b,d',l] * w[h*128+d, d'] + bias   (bf16)
// z==2 (V) stored transposed: Vt[b,h,d,l]
__global__ __launch_bounds__(256) void qkv_proj(
    const float* __restrict__ x,
    const float* __restrict__ wq, const float* __restrict__ wk, const float* __restrict__ wv,
    const float* __restrict__ bq, const float* __restrict__ bk, const float* __restrict__ bv,
    unsigned short* __restrict__ Q, unsigned short* __restrict__ K, unsigned short* __restrict__ Vt)
{
  const int tid = threadIdx.x;
  const int wave = tid >> 6, lane = tid & 63;
  const int lr = lane & 15, lg = lane >> 4;
  const int wr = wave >> 1, wc = wave & 1;
  const int mt = blockIdx.x & 7, nt = blockIdx.x >> 3;
  const int b = blockIdx.y, z = blockIdx.z;
  const int l0 = mt * 128, i0 = nt * 128;
  const float* w    = (z == 0) ? wq : (z == 1) ? wk : wv;
  const float* bias = (z == 0) ? bq : (z == 1) ? bk : bv;
  unsigned short* outp = (z == 0) ? Q : (z == 1) ? K : Vt;

  __shared__ __align__(16) unsigned short lA[128 * 40];  // [l][d] transposed x tile, pad 40
  __shared__ __align__(16) unsigned short lB[128 * 40];  // [i][d] weight tile

  f32x4 acc[4][4];
#pragma unroll
  for (int m = 0; m < 4; ++m)
#pragma unroll
    for (int n = 0; n < 4; ++n) acc[m][n] = (f32x4){0.f, 0.f, 0.f, 0.f};

  const int ad = tid >> 3, aj = tid & 7;  // x staging: row d, col-group
  const int br = tid >> 1, bh2 = tid & 1; // w staging: row i, half

  for (int k0 = 0; k0 < 1024; k0 += 32) {
    const float* xp = x + ((size_t)b * 1024 + k0 + ad) * 1024 + l0;
#pragma unroll
    for (int rep = 0; rep < 4; ++rep) {
      float4 v = *reinterpret_cast<const float4*>(xp + aj * 4 + rep * 32);
      int lb = aj * 4 + rep * 32;
      lA[(lb + 0) * 40 + ad] = f2bf(v.x);
      lA[(lb + 1) * 40 + ad] = f2bf(v.y);
      lA[(lb + 2) * 40 + ad] = f2bf(v.z);
      lA[(lb + 3) * 40 + ad] = f2bf(v.w);
    }
    const float* wp = w + (size_t)(i0 + br) * 1024 + k0 + bh2 * 16;
#pragma unroll
    for (int rep = 0; rep < 4; ++rep) {
      float4 v = *reinterpret_cast<const float4*>(wp + rep * 4);
      int cb = br * 40 + bh2 * 16 + rep * 4;
      lB[cb + 0] = f2bf(v.x); lB[cb + 1] = f2bf(v.y);
      lB[cb + 2] = f2bf(v.z); lB[cb + 3] = f2bf(v.w);
    }
    __syncthreads();
    bf16x8 af[4], bfr[4];
#pragma unroll
    for (int m = 0; m < 4; ++m)
      af[m] = *reinterpret_cast<const bf16x8*>(&lA[(wr * 64 + m * 16 + lr) * 40 + lg * 8]);
#pragma unroll
    for (int n = 0; n < 4; ++n)
      bfr[n] = *reinterpret_cast<const bf16x8*>(&lB[(wc * 64 + n * 16 + lr) * 40 + lg * 8]);
#pragma unroll
    for (int m = 0; m < 4; ++m)
#pragma unroll
      for (int n = 0; n < 4; ++n)
        acc[m][n] = MFMA16(af[m], bfr[n], acc[m][n]);
    __syncthreads();
  }
#pragma unroll
  for (int n = 0; n < 4; ++n) {
    int col = i0 + wc * 64 + n * 16 + lr;
    float bs = bias[col];
    int h = col >> 7, d = col & 127;
#pragma unroll
    for (int m = 0; m < 4; ++m) {
#pragma unroll
      for (int ii = 0; ii < 4; ++ii) {
        int row = l0 + wr * 64 + m * 16 + lg * 4 + ii;
        unsigned short val = f2bf(acc[m][n][ii] + bs);
        if (z < 2)
          outp[(((size_t)b * 8 + h) * 1024 + row) * 128 + d] = val;
        else
          outp[(((size_t)b * 8 + h) * 128 + d) * 1024 + row] = val;
      }
    }
  }
}

// ---------------- Kernel B: flash attention (LDS-staged, 2-phase pipeline) ----
// grid (16 qtiles, 8 heads, 32 batch); 256 thr = 4 waves, 16 q-rows each.
// K tile [64][128] bf16 and V^T tile [128][64] bf16 double-buffered in LDS,
// XOR-swizzled (byte ^= (row&7)<<4) via pre-swizzled global_load_lds source.
__global__ __launch_bounds__(256) void flash_attn(
    const unsigned short* __restrict__ Q, const unsigned short* __restrict__ Kb,
    const unsigned short* __restrict__ Vt, const int* __restrict__ mask,
    unsigned short* __restrict__ O)
{
  const int tid = threadIdx.x, wave = tid >> 6, lane = tid & 63;
  const int lr = lane & 15, lg = lane >> 4;
  const int qt = blockIdx.x, h = blockIdx.y, b = blockIdx.z;
  const size_t bh = (size_t)b * 8 + h;
  const unsigned short* Qp = Q + bh * 131072;
  const unsigned short* Kp = Kb + bh * 131072;
  const unsigned short* Vp = Vt + bh * 131072;
  unsigned short* Op = O + bh * 131072;
  const int q0 = qt * 64 + wave * 16;
  const float SC = 0.08838834764831845f;  // 1/sqrt(128)

  __shared__ __align__(16) unsigned short Kl[2][64 * 128];   // 2 x 16 KiB
  __shared__ __align__(16) unsigned short Vl[2][128 * 64];   // 2 x 16 KiB
  __shared__ __align__(16) unsigned short plds[4][16 * 72];  // per-wave P
  __shared__ float pen[1024];                                // mask penalty

  // mask -> additive penalty (one shot)
  {
    const int4 mv = *reinterpret_cast<const int4*>(mask + b * 1024 + tid * 4);
    float4 pv;
    pv.x = mv.x ? NEGV : 0.f; pv.y = mv.y ? NEGV : 0.f;
    pv.z = mv.z ? NEGV : 0.f; pv.w = mv.w ? NEGV : 0.f;
    *reinterpret_cast<float4*>(&pen[tid * 4]) = pv;
  }

  unsigned short* myP = plds[wave];

  bf16x8 aq[4];
#pragma unroll
  for (int c = 0; c < 4; ++c)
    aq[c] = *reinterpret_cast<const bf16x8*>(&Qp[(size_t)(q0 + lr) * 128 + c * 32 + lg * 8]);

  // staging: dest LDS byte o = i*4096 + tid*16 (linear); source pre-swizzled.
  const int ks_row = (tid >> 4);           // + i*16
  const int ks_cb0 = (tid & 15) * 16;
  const int vs_row = (tid >> 3);           // + i*32
  const int vs_cb0 = (tid & 7) * 16;

#define STAGE(bufi, ktv)                                                        \
  {                                                                             \
    _Pragma("unroll")                                                           \
    for (int i = 0; i < 4; ++i) {                                               \
      int krow = i * 16 + ks_row;                                               \
      int kcb = ks_cb0 ^ ((krow & 7) << 4);                                     \
      gload16(Kp + (size_t)((ktv) + krow) * 128 + (kcb >> 1),                   \
              &Kl[bufi][i * 2048 + wave * 512]);                                \
      int vrow = i * 32 + vs_row;                                               \
      int vcb = vs_cb0 ^ ((vrow & 7) << 4);                                     \
      gload16(Vp + (size_t)vrow * 1024 + (ktv) + (vcb >> 1),                    \
              &Vl[bufi][i * 2048 + wave * 512]);                                \
    }                                                                           \
  }

  f32x4 oacc[8];
#pragma unroll
  for (int dt = 0; dt < 8; ++dt) oacc[dt] = (f32x4){0.f, 0.f, 0.f, 0.f};
  float mrun[4] = {NEGV, NEGV, NEGV, NEGV};
  float lrun[4] = {0.f, 0.f, 0.f, 0.f};

  STAGE(0, 0);
  __syncthreads();  // drains vmcnt(0): tile 0 + penalty ready

  int cur = 0;
  for (int t = 0; t < 16; ++t) {
    const int kt = t * 64;
    if (t < 15) STAGE(cur ^ 1, kt + 64);  // prefetch next tile under compute

    // ---- S = Q K^T (swizzled LDS reads) ----
    f32x4 s[4];
    __builtin_amdgcn_s_setprio(1);
#pragma unroll
    for (int n = 0; n < 4; ++n) {
      f32x4 a = (f32x4){0.f, 0.f, 0.f, 0.f};
      const int krow = n * 16 + lr;
      const int rsw = (krow & 7) << 4;
#pragma unroll
      for (int c = 0; c < 4; ++c) {
        bf16x8 bk = *reinterpret_cast<const bf16x8*>(
            &Kl[cur][krow * 128 + (((c * 64 + lg * 16) ^ rsw) >> 1)]);
        a = MFMA16(aq[c], bk, a);
      }
      s[n] = a;
    }
    __builtin_amdgcn_s_setprio(0);

    // ---- scale + mask ----
#pragma unroll
    for (int n = 0; n < 4; ++n) {
      float pn = pen[kt + n * 16 + lr];
#pragma unroll
      for (int i = 0; i < 4; ++i) s[n][i] = s[n][i] * SC + pn;
    }

    // ---- online softmax (row i across 16 lanes of each lane-group) ----
    float p[4][4];
#pragma unroll
    for (int i = 0; i < 4; ++i) {
      float mx = fmaxf(fmaxf(s[0][i], s[1][i]), fmaxf(s[2][i], s[3][i]));
      mx = fmaxf(mx, __shfl_xor(mx, 1));
      mx = fmaxf(mx, __shfl_xor(mx, 2));
      mx = fmaxf(mx, __shfl_xor(mx, 4));
      mx = fmaxf(mx, __shfl_xor(mx, 8));
      float mnew = fmaxf(mrun[i], mx);
      float sc = __expf(mrun[i] - mnew);
      mrun[i] = mnew;
      float ps = 0.f;
#pragma unroll
      for (int n = 0; n < 4; ++n) {
        float pv = __expf(s[n][i] - mnew);
        p[n][i] = pv;
        ps += pv;
      }
      ps += __shfl_xor(ps, 1); ps += __shfl_xor(ps, 2);
      ps += __shfl_xor(ps, 4); ps += __shfl_xor(ps, 8);
      lrun[i] = lrun[i] * sc + ps;
#pragma unroll
      for (int dt = 0; dt < 8; ++dt) oacc[dt][i] *= sc;
    }

    // ---- P (D-layout) -> per-wave LDS -> A-frag layout (wave-internal) ----
#pragma unroll
    for (int n = 0; n < 4; ++n)
#pragma unroll
      for (int i = 0; i < 4; ++i)
        myP[(lg * 4 + i) * 72 + n * 16 + lr] = f2bf(p[n][i]);
    bf16x8 pa0 = *reinterpret_cast<const bf16x8*>(&myP[lr * 72 + lg * 8]);
    bf16x8 pa1 = *reinterpret_cast<const bf16x8*>(&myP[lr * 72 + 32 + lg * 8]);

    // ---- O += P V (swizzled LDS reads of V^T tile) ----
    __builtin_amdgcn_s_setprio(1);
#pragma unroll
    for (int dt = 0; dt < 8; ++dt) {
      const int vrow = dt * 16 + lr;
      const int rsw = (vrow & 7) << 4;
      bf16x8 bv0 = *reinterpret_cast<const bf16x8*>(
          &Vl[cur][vrow * 64 + (((lg * 16) ^ rsw) >> 1)]);
      bf16x8 bv1 = *reinterpret_cast<const bf16x8*>(
          &Vl[cur][vrow * 64 + (((64 + lg * 16) ^ rsw) >> 1)]);
      oacc[dt] = MFMA16(pa0, bv0, oacc[dt]);
      oacc[dt] = MFMA16(pa1, bv1, oacc[dt]);
    }
    __builtin_amdgcn_s_setprio(0);

    __syncthreads();  // vmcnt(0)+lgkmcnt(0) drain: prefetched tile ready, reads done
    cur ^= 1;
  }

  float inv[4];
#pragma unroll
  for (int i = 0; i < 4; ++i) inv[i] = 1.f / lrun[i];
#pragma unroll
  for (int dt = 0; dt < 8; ++dt)
#pragma unroll
    for (int i = 0; i < 4; ++i)
      Op[(size_t)(q0 + lg * 4 + i) * 128 + dt * 16 + lr] = f2bf(oacc[dt][i] * inv[i]);
}

// ---------------- Kernel C: output projection ----------------
__global__ __launch_bounds__(256) void out_proj(
    const unsigned short* __restrict__ Obuf, const float* __restrict__ wo,
    const float* __restrict__ bo, float* __restrict__ out)
{
  const int tid = threadIdx.x, wave = tid >> 6, lane = tid & 63;
  const int lr = lane & 15, lg = lane >> 4;
  const int wr = wave >> 1, wc = wave & 1;
  const int mt = blockIdx.x & 7, nt = blockIdx.x >> 3;
  const int b = blockIdx.y;
  const int d0 = mt * 128, l0 = nt * 128;

  __shared__ __align__(16) unsigned short lA[128 * 40];
  __shared__ __align__(16) unsigned short lB[128 * 40];

  f32x4 acc[4][4];
#pragma unroll
  for (int m = 0; m < 4; ++m)
#pragma unroll
    for (int n = 0; n < 4; ++n) acc[m][n] = (f32x4){0.f, 0.f, 0.f, 0.f};

  const int ar = tid >> 1, ah = tid & 1;

  for (int k0 = 0; k0 < 1024; k0 += 32) {
    const float* wp = wo + (size_t)(d0 + ar) * 1024 + k0 + ah * 16;
#pragma unroll
    for (int rep = 0; rep < 4; ++rep) {
      float4 v = *reinterpret_cast<const float4*>(wp + rep * 4);
      int cb = ar * 40 + ah * 16 + rep * 4;
      lA[cb + 0] = f2bf(v.x); lA[cb + 1] = f2bf(v.y);
      lA[cb + 2] = f2bf(v.z); lA[cb + 3] = f2bf(v.w);
    }
    {
      int head = k0 >> 7, dk = (k0 & 127) + ah * 16;
      const unsigned short* op =
          Obuf + (((size_t)b * 8 + head) * 1024 + l0 + ar) * 128 + dk;
#pragma unroll
      for (int rep = 0; rep < 2; ++rep) {
        bf16x8 v = *reinterpret_cast<const bf16x8*>(op + rep * 8);
        *reinterpret_cast<bf16x8*>(&lB[ar * 40 + ah * 16 + rep * 8]) = v;
      }
    }
    __syncthreads();
    bf16x8 af[4], bfr[4];
#pragma unroll
    for (int m = 0; m < 4; ++m)
      af[m] = *reinterpret_cast<const bf16x8*>(&lA[(wr * 64 + m * 16 + lr) * 40 + lg * 8]);
#pragma unroll
    for (int n = 0; n < 4; ++n)
      bfr[n] = *reinterpret_cast<const bf16x8*>(&lB[(wc * 64 + n * 16 + lr) * 40 + lg * 8]);
#pragma unroll
    for (int m = 0; m < 4; ++m)
#pragma unroll
      for (int n = 0; n < 4; ++n)
        acc[m][n] = MFMA16(af[m], bfr[n], acc[m][n]);
    __syncthreads();
  }
#pragma unroll
  for (int m = 0; m < 4; ++m) {
#pragma unroll
    for (int ii = 0; ii < 4; ++ii) {
      int dr = d0 + wr * 64 + m * 16 + lg * 4 + ii;
      float bs = bo[dr];
      float* orow = out + ((size_t)b * 1024 + dr) * 1024 + l0 + wc * 64 + lr;
#pragma unroll
      for (int n = 0; n < 4; ++n)
        orow[n * 16] = acc[m][n][ii] + bs;
    }
  }
}

extern "C" void kernel_launch(void* const* d_in, const int* in_sizes, int n_in,
                              void* d_out, int out_size, void* d_ws, size_t ws_size,
                              hipStream_t stream) {
  const float* x  = (const float*)d_in[0];
  const int* mask = (const int*)d_in[1];
  const float* wq = (const float*)d_in[2];
  const float* bq = (const float*)d_in[3];
  const float* wk = (const float*)d_in[4];
  const float* bk = (const float*)d_in[5];
  const float* wv = (const float*)d_in[6];
  const float* bv = (const float*)d_in[7];
  const float* wo = (const float*)d_in[8];
  const float* bo = (const float*)d_in[9];
  float* out = (float*)d_out;

  unsigned short* Q  = (unsigned short*)d_ws;          // [32][8][1024][128] bf16, later O
  unsigned short* K  = Q + (size_t)33554432;           // 64 MiB each
  unsigned short* Vt = K + (size_t)33554432;           // V transposed [32][8][128][1024]

  qkv_proj<<<dim3(64, 32, 3), 256, 0, stream>>>(x, wq, wk, wv, bq, bk, bv, Q, K, Vt);
  flash_attn<<<dim3(16, 8, 32), 256, 0, stream>>>(Q, K, Vt, mask, Q /* O aliases Q */);
  out_proj<<<dim3(64, 32), 256, 0, stream>>>(Q, wo, bo, out);
}

// Round 3
// 828.306 us; speedup vs baseline: 2.1252x; 1.2048x over previous
//
#include <hip/hip_runtime.h>
#include <hip/hip_bf16.h>

typedef __bf16 bf16_t;
typedef bf16_t bf16x8 __attribute__((ext_vector_type(8)));
typedef float f32x4 __attribute__((ext_vector_type(4)));

#define MFMA16(a, b, c) __builtin_amdgcn_mfma_f32_16x16x32_bf16(a, b, c, 0, 0, 0)
#define NEGV -1e30f

__device__ __forceinline__ unsigned short f2bf(float f) {
  union { float f; unsigned int u; } v; v.f = f;
  unsigned int r = v.u + 0x7FFFu + ((v.u >> 16) & 1u);
  return (unsigned short)(r >> 16);
}

__device__ __forceinline__ void gload16(const unsigned short* g, unsigned short* l) {
  __builtin_amdgcn_global_load_lds(
      (const __attribute__((address_space(1))) void*)g,
      (__attribute__((address_space(3))) void*)l, 16, 0, 0);
}

// ============ Kernel P1: x [B,D,L] fp32 -> xT [B,L,D] bf16 ============
__global__ __launch_bounds__(256) void x_transpose(
    const float* __restrict__ x, unsigned short* __restrict__ xT)
{
  const int b = blockIdx.z;
  const int l0 = blockIdx.x * 64, d0 = blockIdx.y * 64;
  __shared__ __align__(16) unsigned short T[64][68];
  const int tid = threadIdx.x;
  const int dl = tid >> 4, lc = (tid & 15) * 4;
#pragma unroll
  for (int rep = 0; rep < 4; ++rep) {
    int d = dl + rep * 16;
    float4 v = *reinterpret_cast<const float4*>(
        x + ((size_t)b * 1024 + d0 + d) * 1024 + l0 + lc);
    ushort4 u;
    u.x = f2bf(v.x); u.y = f2bf(v.y); u.z = f2bf(v.z); u.w = f2bf(v.w);
    *reinterpret_cast<ushort4*>(&T[d][lc]) = u;
  }
  __syncthreads();
  const int dbase = (tid & 15) * 4, lbase = (tid >> 4) * 4;
  ushort4 r0 = *reinterpret_cast<const ushort4*>(&T[dbase + 0][lbase]);
  ushort4 r1 = *reinterpret_cast<const ushort4*>(&T[dbase + 1][lbase]);
  ushort4 r2 = *reinterpret_cast<const ushort4*>(&T[dbase + 2][lbase]);
  ushort4 r3 = *reinterpret_cast<const ushort4*>(&T[dbase + 3][lbase]);
  ushort4 w0 = {r0.x, r1.x, r2.x, r3.x};
  ushort4 w1 = {r0.y, r1.y, r2.y, r3.y};
  ushort4 w2 = {r0.z, r1.z, r2.z, r3.z};
  ushort4 w3 = {r0.w, r1.w, r2.w, r3.w};
  unsigned short* op = xT + ((size_t)b * 1024 + l0 + lbase) * 1024 + d0 + dbase;
  *reinterpret_cast<ushort4*>(op) = w0;
  *reinterpret_cast<ushort4*>(op + 1024) = w1;
  *reinterpret_cast<ushort4*>(op + 2048) = w2;
  *reinterpret_cast<ushort4*>(op + 3072) = w3;
}

// ============ Kernel P2: weights fp32 -> bf16 (Wqkv concat + Wo) ============
__global__ __launch_bounds__(256) void w_convert(
    const float* __restrict__ wq, const float* __restrict__ wk,
    const float* __restrict__ wv, const float* __restrict__ wo,
    unsigned short* __restrict__ Wqkv, unsigned short* __restrict__ Wo)
{
  const int z = blockIdx.y;
  const float* src = (z == 0) ? wq : (z == 1) ? wk : (z == 2) ? wv : wo;
  unsigned short* dst = (z < 3) ? Wqkv + (size_t)z * 1048576 : Wo;
  size_t off = ((size_t)blockIdx.x * 256 + threadIdx.x) * 4;
  float4 v = *reinterpret_cast<const float4*>(src + off);
  ushort4 u = {f2bf(v.x), f2bf(v.y), f2bf(v.z), f2bf(v.w)};
  *reinterpret_cast<ushort4*>(dst + off) = u;
}

// ============ Kernel A: fused QKV GEMM (m97 structure) ============
// C[l, n] = xT[b,l,:] . Wqkv[n,:], n in [0,3072). 128x128 tile, BK=64.
__global__ __launch_bounds__(256) void qkv_gemm(
    const unsigned short* __restrict__ xT, const unsigned short* __restrict__ Wqkv,
    const float* __restrict__ bq, const float* __restrict__ bk, const float* __restrict__ bv,
    unsigned short* __restrict__ Q, unsigned short* __restrict__ K,
    unsigned short* __restrict__ Vt)
{
  const int tid = threadIdx.x;
  const int wave = tid >> 6, lane = tid & 63;
  const int lr = lane & 15, lg = lane >> 4;
  const int wr = wave >> 1, wc = wave & 1;
  const int mt = blockIdx.x & 7, nt = blockIdx.x >> 3;  // 8 x 24
  const int b = blockIdx.y;
  const int l0 = mt * 128, n0 = nt * 128;
  const unsigned short* Ap = xT + ((size_t)b << 20) + (size_t)l0 * 1024;
  const unsigned short* Bp = Wqkv + (size_t)n0 * 1024;

  __shared__ __align__(16) unsigned short lA[128 * 64];
  __shared__ __align__(16) unsigned short lB[128 * 64];

  f32x4 acc[4][4];
#pragma unroll
  for (int m = 0; m < 4; ++m)
#pragma unroll
    for (int n = 0; n < 4; ++n) acc[m][n] = (f32x4){0.f, 0.f, 0.f, 0.f};

  const int srow = tid >> 3, scol = (tid & 7) * 8;

  for (int k0 = 0; k0 < 1024; k0 += 64) {
#pragma unroll
    for (int i = 0; i < 4; ++i) {
      gload16(Ap + (size_t)(i * 32 + srow) * 1024 + k0 + scol, &lA[i * 2048 + tid * 8]);
      gload16(Bp + (size_t)(i * 32 + srow) * 1024 + k0 + scol, &lB[i * 2048 + tid * 8]);
    }
    __syncthreads();
    bf16x8 af[2][4], bfr[2][4];
#pragma unroll
    for (int kk = 0; kk < 2; ++kk) {
#pragma unroll
      for (int m = 0; m < 4; ++m)
        af[kk][m] = *reinterpret_cast<const bf16x8*>(
            &lA[(wr * 64 + m * 16 + lr) * 64 + kk * 32 + lg * 8]);
#pragma unroll
      for (int n = 0; n < 4; ++n)
        bfr[kk][n] = *reinterpret_cast<const bf16x8*>(
            &lB[(wc * 64 + n * 16 + lr) * 64 + kk * 32 + lg * 8]);
    }
#pragma unroll
    for (int kk = 0; kk < 2; ++kk)
#pragma unroll
      for (int m = 0; m < 4; ++m)
#pragma unroll
        for (int n = 0; n < 4; ++n)
          acc[m][n] = MFMA16(af[kk][m], bfr[kk][n], acc[m][n]);
    __syncthreads();
  }

  // n-range [n0, n0+128) lies in one z and one head (n0 % 128 == 0)
  const int zi = n0 >> 10;
  const int h = (n0 & 1023) >> 7;
  const float* bias = (zi == 0) ? bq : (zi == 1) ? bk : bv;
  const size_t bhbase = ((size_t)b * 8 + h) * 131072;

  if (zi < 2) {
    unsigned short* op = ((zi == 0) ? Q : K) + bhbase;
#pragma unroll
    for (int n = 0; n < 4; ++n) {
      const int d = wc * 64 + n * 16 + lr;
      const float bs = bias[h * 128 + d];
#pragma unroll
      for (int m = 0; m < 4; ++m)
#pragma unroll
        for (int ii = 0; ii < 4; ++ii) {
          int l = l0 + wr * 64 + m * 16 + lg * 4 + ii;
          op[(size_t)l * 128 + d] = f2bf(acc[m][n][ii] + bs);
        }
    }
  } else {
#pragma unroll
    for (int n = 0; n < 4; ++n) {
      const int d = wc * 64 + n * 16 + lr;
      const float bs = bias[h * 128 + d];
#pragma unroll
      for (int m = 0; m < 4; ++m) {
        int l = l0 + wr * 64 + m * 16 + lg * 4;
        ushort4 u = {f2bf(acc[m][n][0] + bs), f2bf(acc[m][n][1] + bs),
                     f2bf(acc[m][n][2] + bs), f2bf(acc[m][n][3] + bs)};
        *reinterpret_cast<ushort4*>(&Vt[bhbase + (size_t)d * 1024 + l]) = u;
      }
    }
  }
}

// ============ Kernel C: output projection GEMM (m97 structure) ============
// out[b,d,l] = Wo[d,:] . O'[l,:] + bo[d], O' = attention output [b,h,l,dh]
__global__ __launch_bounds__(256) void out_gemm(
    const unsigned short* __restrict__ Wo, const unsigned short* __restrict__ O,
    const float* __restrict__ bo, float* __restrict__ out)
{
  const int tid = threadIdx.x;
  const int wave = tid >> 6, lane = tid & 63;
  const int lr = lane & 15, lg = lane >> 4;
  const int wr = wave >> 1, wc = wave & 1;
  const int mt = blockIdx.x & 7, nt = blockIdx.x >> 3;  // d-tiles x l-tiles
  const int b = blockIdx.y;
  const int d0 = mt * 128, l0 = nt * 128;
  const unsigned short* Ap = Wo + (size_t)d0 * 1024;

  __shared__ __align__(16) unsigned short lA[128 * 64];
  __shared__ __align__(16) unsigned short lB[128 * 64];

  f32x4 acc[4][4];
#pragma unroll
  for (int m = 0; m < 4; ++m)
#pragma unroll
    for (int n = 0; n < 4; ++n) acc[m][n] = (f32x4){0.f, 0.f, 0.f, 0.f};

  const int srow = tid >> 3, scol = (tid & 7) * 8;

  for (int k0 = 0; k0 < 1024; k0 += 64) {
    const unsigned short* Bp =
        O + (((size_t)b * 8 + (k0 >> 7)) * 1024 + l0) * 128 + (k0 & 64);
#pragma unroll
    for (int i = 0; i < 4; ++i) {
      gload16(Ap + (size_t)(i * 32 + srow) * 1024 + k0 + scol, &lA[i * 2048 + tid * 8]);
      gload16(Bp + (size_t)(i * 32 + srow) * 128 + scol, &lB[i * 2048 + tid * 8]);
    }
    __syncthreads();
    bf16x8 af[2][4], bfr[2][4];
#pragma unroll
    for (int kk = 0; kk < 2; ++kk) {
#pragma unroll
      for (int m = 0; m < 4; ++m)
        af[kk][m] = *reinterpret_cast<const bf16x8*>(
            &lA[(wr * 64 + m * 16 + lr) * 64 + kk * 32 + lg * 8]);
#pragma unroll
      for (int n = 0; n < 4; ++n)
        bfr[kk][n] = *reinterpret_cast<const bf16x8*>(
            &lB[(wc * 64 + n * 16 + lr) * 64 + kk * 32 + lg * 8]);
    }
#pragma unroll
    for (int kk = 0; kk < 2; ++kk)
#pragma unroll
      for (int m = 0; m < 4; ++m)
#pragma unroll
        for (int n = 0; n < 4; ++n)
          acc[m][n] = MFMA16(af[kk][m], bfr[kk][n], acc[m][n]);
    __syncthreads();
  }

#pragma unroll
  for (int m = 0; m < 4; ++m) {
#pragma unroll
    for (int ii = 0; ii < 4; ++ii) {
      int dr = d0 + wr * 64 + m * 16 + lg * 4 + ii;
      float bs = bo[dr];
      float* orow = out + ((size_t)b * 1024 + dr) * 1024 + l0 + wc * 64 + lr;
#pragma unroll
      for (int n = 0; n < 4; ++n)
        orow[n * 16] = acc[m][n][ii] + bs;
    }
  }
}

// ============ Kernel B: flash attention (LDS-staged, 2-phase pipeline) ======
__global__ __launch_bounds__(256) void flash_attn(
    const unsigned short* __restrict__ Q, const unsigned short* __restrict__ Kb,
    const unsigned short* __restrict__ Vt, const int* __restrict__ mask,
    unsigned short* __restrict__ O)
{
  const int tid = threadIdx.x, wave = tid >> 6, lane = tid & 63;
  const int lr = lane & 15, lg = lane >> 4;
  const int qt = blockIdx.x, h = blockIdx.y, b = blockIdx.z;
  const size_t bh = (size_t)b * 8 + h;
  const unsigned short* Qp = Q + bh * 131072;
  const unsigned short* Kp = Kb + bh * 131072;
  const unsigned short* Vp = Vt + bh * 131072;
  unsigned short* Op = O + bh * 131072;
  const int q0 = qt * 64 + wave * 16;
  const float SC = 0.08838834764831845f;  // 1/sqrt(128)

  __shared__ __align__(16) unsigned short Kl[2][64 * 128];
  __shared__ __align__(16) unsigned short Vl[2][128 * 64];
  __shared__ __align__(16) unsigned short plds[4][16 * 72];
  __shared__ float pen[1024];

  {
    const int4 mv = *reinterpret_cast<const int4*>(mask + b * 1024 + tid * 4);
    float4 pv;
    pv.x = mv.x ? NEGV : 0.f; pv.y = mv.y ? NEGV : 0.f;
    pv.z = mv.z ? NEGV : 0.f; pv.w = mv.w ? NEGV : 0.f;
    *reinterpret_cast<float4*>(&pen[tid * 4]) = pv;
  }

  unsigned short* myP = plds[wave];

  bf16x8 aq[4];
#pragma unroll
  for (int c = 0; c < 4; ++c)
    aq[c] = *reinterpret_cast<const bf16x8*>(&Qp[(size_t)(q0 + lr) * 128 + c * 32 + lg * 8]);

  const int ks_row = (tid >> 4);
  const int ks_cb0 = (tid & 15) * 16;
  const int vs_row = (tid >> 3);
  const int vs_cb0 = (tid & 7) * 16;

#define STAGE(bufi, ktv)                                                        \
  {                                                                             \
    _Pragma("unroll")                                                           \
    for (int i = 0; i < 4; ++i) {                                               \
      int krow = i * 16 + ks_row;                                               \
      int kcb = ks_cb0 ^ ((krow & 7) << 4);                                     \
      gload16(Kp + (size_t)((ktv) + krow) * 128 + (kcb >> 1),                   \
              &Kl[bufi][i * 2048 + wave * 512]);                                \
      int vrow = i * 32 + vs_row;                                               \
      int vcb = vs_cb0 ^ ((vrow & 7) << 4);                                     \
      gload16(Vp + (size_t)vrow * 1024 + (ktv) + (vcb >> 1),                    \
              &Vl[bufi][i * 2048 + wave * 512]);                                \
    }                                                                           \
  }

  f32x4 oacc[8];
#pragma unroll
  for (int dt = 0; dt < 8; ++dt) oacc[dt] = (f32x4){0.f, 0.f, 0.f, 0.f};
  float mrun[4] = {NEGV, NEGV, NEGV, NEGV};
  float lrun[4] = {0.f, 0.f, 0.f, 0.f};

  STAGE(0, 0);
  __syncthreads();

  int cur = 0;
  for (int t = 0; t < 16; ++t) {
    const int kt = t * 64;
    if (t < 15) STAGE(cur ^ 1, kt + 64);

    f32x4 s[4];
    __builtin_amdgcn_s_setprio(1);
#pragma unroll
    for (int n = 0; n < 4; ++n) {
      f32x4 a = (f32x4){0.f, 0.f, 0.f, 0.f};
      const int krow = n * 16 + lr;
      const int rsw = (krow & 7) << 4;
#pragma unroll
      for (int c = 0; c < 4; ++c) {
        bf16x8 bk = *reinterpret_cast<const bf16x8*>(
            &Kl[cur][krow * 128 + (((c * 64 + lg * 16) ^ rsw) >> 1)]);
        a = MFMA16(aq[c], bk, a);
      }
      s[n] = a;
    }
    __builtin_amdgcn_s_setprio(0);

#pragma unroll
    for (int n = 0; n < 4; ++n) {
      float pn = pen[kt + n * 16 + lr];
#pragma unroll
      for (int i = 0; i < 4; ++i) s[n][i] = s[n][i] * SC + pn;
    }

    float p[4][4];
#pragma unroll
    for (int i = 0; i < 4; ++i) {
      float mx = fmaxf(fmaxf(s[0][i], s[1][i]), fmaxf(s[2][i], s[3][i]));
      mx = fmaxf(mx, __shfl_xor(mx, 1));
      mx = fmaxf(mx, __shfl_xor(mx, 2));
      mx = fmaxf(mx, __shfl_xor(mx, 4));
      mx = fmaxf(mx, __shfl_xor(mx, 8));
      float mnew = fmaxf(mrun[i], mx);
      float sc = __expf(mrun[i] - mnew);
      mrun[i] = mnew;
      float ps = 0.f;
#pragma unroll
      for (int n = 0; n < 4; ++n) {
        float pv = __expf(s[n][i] - mnew);
        p[n][i] = pv;
        ps += pv;
      }
      ps += __shfl_xor(ps, 1); ps += __shfl_xor(ps, 2);
      ps += __shfl_xor(ps, 4); ps += __shfl_xor(ps, 8);
      lrun[i] = lrun[i] * sc + ps;
#pragma unroll
      for (int dt = 0; dt < 8; ++dt) oacc[dt][i] *= sc;
    }

#pragma unroll
    for (int n = 0; n < 4; ++n)
#pragma unroll
      for (int i = 0; i < 4; ++i)
        myP[(lg * 4 + i) * 72 + n * 16 + lr] = f2bf(p[n][i]);
    bf16x8 pa0 = *reinterpret_cast<const bf16x8*>(&myP[lr * 72 + lg * 8]);
    bf16x8 pa1 = *reinterpret_cast<const bf16x8*>(&myP[lr * 72 + 32 + lg * 8]);

    __builtin_amdgcn_s_setprio(1);
#pragma unroll
    for (int dt = 0; dt < 8; ++dt) {
      const int vrow = dt * 16 + lr;
      const int rsw = (vrow & 7) << 4;
      bf16x8 bv0 = *reinterpret_cast<const bf16x8*>(
          &Vl[cur][vrow * 64 + (((lg * 16) ^ rsw) >> 1)]);
      bf16x8 bv1 = *reinterpret_cast<const bf16x8*>(
          &Vl[cur][vrow * 64 + (((64 + lg * 16) ^ rsw) >> 1)]);
      oacc[dt] = MFMA16(pa0, bv0, oacc[dt]);
      oacc[dt] = MFMA16(pa1, bv1, oacc[dt]);
    }
    __builtin_amdgcn_s_setprio(0);

    __syncthreads();
    cur ^= 1;
  }

  float inv[4];
#pragma unroll
  for (int i = 0; i < 4; ++i) inv[i] = 1.f / lrun[i];
#pragma unroll
  for (int dt = 0; dt < 8; ++dt)
#pragma unroll
    for (int i = 0; i < 4; ++i)
      Op[(size_t)(q0 + lg * 4 + i) * 128 + dt * 16 + lr] = f2bf(oacc[dt][i] * inv[i]);
}

// ============ Fallback kernels (round-2, 192 MiB workspace) ============
__global__ __launch_bounds__(256) void qkv_proj_old(
    const float* __restrict__ x,
    const float* __restrict__ wq, const float* __restrict__ wk, const float* __restrict__ wv,
    const float* __restrict__ bq, const float* __restrict__ bk, const float* __restrict__ bv,
    unsigned short* __restrict__ Q, unsigned short* __restrict__ K, unsigned short* __restrict__ Vt)
{
  const int tid = threadIdx.x;
  const int wave = tid >> 6, lane = tid & 63;
  const int lr = lane & 15, lg = lane >> 4;
  const int wr = wave >> 1, wc = wave & 1;
  const int mt = blockIdx.x & 7, nt = blockIdx.x >> 3;
  const int b = blockIdx.y, z = blockIdx.z;
  const int l0 = mt * 128, i0 = nt * 128;
  const float* w    = (z == 0) ? wq : (z == 1) ? wk : wv;
  const float* bias = (z == 0) ? bq : (z == 1) ? bk : bv;
  unsigned short* outp = (z == 0) ? Q : (z == 1) ? K : Vt;

  __shared__ __align__(16) unsigned short lA[128 * 40];
  __shared__ __align__(16) unsigned short lB[128 * 40];

  f32x4 acc[4][4];
#pragma unroll
  for (int m = 0; m < 4; ++m)
#pragma unroll
    for (int n = 0; n < 4; ++n) acc[m][n] = (f32x4){0.f, 0.f, 0.f, 0.f};

  const int ad = tid >> 3, aj = tid & 7;
  const int br = tid >> 1, bh2 = tid & 1;

  for (int k0 = 0; k0 < 1024; k0 += 32) {
    const float* xp = x + ((size_t)b * 1024 + k0 + ad) * 1024 + l0;
#pragma unroll
    for (int rep = 0; rep < 4; ++rep) {
      float4 v = *reinterpret_cast<const float4*>(xp + aj * 4 + rep * 32);
      int lb = aj * 4 + rep * 32;
      lA[(lb + 0) * 40 + ad] = f2bf(v.x);
      lA[(lb + 1) * 40 + ad] = f2bf(v.y);
      lA[(lb + 2) * 40 + ad] = f2bf(v.z);
      lA[(lb + 3) * 40 + ad] = f2bf(v.w);
    }
    const float* wp = w + (size_t)(i0 + br) * 1024 + k0 + bh2 * 16;
#pragma unroll
    for (int rep = 0; rep < 4; ++rep) {
      float4 v = *reinterpret_cast<const float4*>(wp + rep * 4);
      int cb = br * 40 + bh2 * 16 + rep * 4;
      lB[cb + 0] = f2bf(v.x); lB[cb + 1] = f2bf(v.y);
      lB[cb + 2] = f2bf(v.z); lB[cb + 3] = f2bf(v.w);
    }
    __syncthreads();
    bf16x8 af[4], bfr[4];
#pragma unroll
    for (int m = 0; m < 4; ++m)
      af[m] = *reinterpret_cast<const bf16x8*>(&lA[(wr * 64 + m * 16 + lr) * 40 + lg * 8]);
#pragma unroll
    for (int n = 0; n < 4; ++n)
      bfr[n] = *reinterpret_cast<const bf16x8*>(&lB[(wc * 64 + n * 16 + lr) * 40 + lg * 8]);
#pragma unroll
    for (int m = 0; m < 4; ++m)
#pragma unroll
      for (int n = 0; n < 4; ++n)
        acc[m][n] = MFMA16(af[m], bfr[n], acc[m][n]);
    __syncthreads();
  }
#pragma unroll
  for (int n = 0; n < 4; ++n) {
    int col = i0 + wc * 64 + n * 16 + lr;
    float bs = bias[col];
    int h = col >> 7, d = col & 127;
#pragma unroll
    for (int m = 0; m < 4; ++m) {
#pragma unroll
      for (int ii = 0; ii < 4; ++ii) {
        int row = l0 + wr * 64 + m * 16 + lg * 4 + ii;
        unsigned short val = f2bf(acc[m][n][ii] + bs);
        if (z < 2)
          outp[(((size_t)b * 8 + h) * 1024 + row) * 128 + d] = val;
        else
          outp[(((size_t)b * 8 + h) * 128 + d) * 1024 + row] = val;
      }
    }
  }
}

__global__ __launch_bounds__(256) void out_proj_old(
    const unsigned short* __restrict__ Obuf, const float* __restrict__ wo,
    const float* __restrict__ bo, float* __restrict__ out)
{
  const int tid = threadIdx.x, wave = tid >> 6, lane = tid & 63;
  const int lr = lane & 15, lg = lane >> 4;
  const int wr = wave >> 1, wc = wave & 1;
  const int mt = blockIdx.x & 7, nt = blockIdx.x >> 3;
  const int b = blockIdx.y;
  const int d0 = mt * 128, l0 = nt * 128;

  __shared__ __align__(16) unsigned short lA[128 * 40];
  __shared__ __align__(16) unsigned short lB[128 * 40];

  f32x4 acc[4][4];
#pragma unroll
  for (int m = 0; m < 4; ++m)
#pragma unroll
    for (int n = 0; n < 4; ++n) acc[m][n] = (f32x4){0.f, 0.f, 0.f, 0.f};

  const int ar = tid >> 1, ah = tid & 1;

  for (int k0 = 0; k0 < 1024; k0 += 32) {
    const float* wp = wo + (size_t)(d0 + ar) * 1024 + k0 + ah * 16;
#pragma unroll
    for (int rep = 0; rep < 4; ++rep) {
      float4 v = *reinterpret_cast<const float4*>(wp + rep * 4);
      int cb = ar * 40 + ah * 16 + rep * 4;
      lA[cb + 0] = f2bf(v.x); lA[cb + 1] = f2bf(v.y);
      lA[cb + 2] = f2bf(v.z); lA[cb + 3] = f2bf(v.w);
    }
    {
      int head = k0 >> 7, dk = (k0 & 127) + ah * 16;
      const unsigned short* op =
          Obuf + (((size_t)b * 8 + head) * 1024 + l0 + ar) * 128 + dk;
#pragma unroll
      for (int rep = 0; rep < 2; ++rep) {
        bf16x8 v = *reinterpret_cast<const bf16x8*>(op + rep * 8);
        *reinterpret_cast<bf16x8*>(&lB[ar * 40 + ah * 16 + rep * 8]) = v;
      }
    }
    __syncthreads();
    bf16x8 af[4], bfr[4];
#pragma unroll
    for (int m = 0; m < 4; ++m)
      af[m] = *reinterpret_cast<const bf16x8*>(&lA[(wr * 64 + m * 16 + lr) * 40 + lg * 8]);
#pragma unroll
    for (int n = 0; n < 4; ++n)
      bfr[n] = *reinterpret_cast<const bf16x8*>(&lB[(wc * 64 + n * 16 + lr) * 40 + lg * 8]);
#pragma unroll
    for (int m = 0; m < 4; ++m)
#pragma unroll
      for (int n = 0; n < 4; ++n)
        acc[m][n] = MFMA16(af[m], bfr[n], acc[m][n]);
    __syncthreads();
  }
#pragma unroll
  for (int m = 0; m < 4; ++m) {
#pragma unroll
    for (int ii = 0; ii < 4; ++ii) {
      int dr = d0 + wr * 64 + m * 16 + lg * 4 + ii;
      float bs = bo[dr];
      float* orow = out + ((size_t)b * 1024 + dr) * 1024 + l0 + wc * 64 + lr;
#pragma unroll
      for (int n = 0; n < 4; ++n)
        orow[n * 16] = acc[m][n][ii] + bs;
    }
  }
}

extern "C" void kernel_launch(void* const* d_in, const int* in_sizes, int n_in,
                              void* d_out, int out_size, void* d_ws, size_t ws_size,
                              hipStream_t stream) {
  const float* x  = (const float*)d_in[0];
  const int* mask = (const int*)d_in[1];
  const float* wq = (const float*)d_in[2];
  const float* bq = (const float*)d_in[3];
  const float* wk = (const float*)d_in[4];
  const float* bk = (const float*)d_in[5];
  const float* wv = (const float*)d_in[6];
  const float* bv = (const float*)d_in[7];
  const float* wo = (const float*)d_in[8];
  const float* bo = (const float*)d_in[9];
  float* out = (float*)d_out;

  const size_t MB64 = (size_t)64 << 20;
  const size_t NEED = (size_t)264 << 20;

  if (ws_size >= NEED) {
    unsigned short* xT   = (unsigned short*)d_ws;                  // 64 MiB
    unsigned short* Q    = (unsigned short*)((char*)d_ws + MB64);  // 64 MiB (later O)
    unsigned short* K    = (unsigned short*)((char*)d_ws + 2 * MB64);
    unsigned short* Vt   = (unsigned short*)((char*)d_ws + 3 * MB64);
    unsigned short* Wqkv = (unsigned short*)((char*)d_ws + 4 * MB64);  // 6 MiB
    unsigned short* Wo   = Wqkv + (size_t)3 * 1048576;                 // 2 MiB

    x_transpose<<<dim3(16, 16, 32), 256, 0, stream>>>(x, xT);
    w_convert<<<dim3(1024, 4), 256, 0, stream>>>(wq, wk, wv, wo, Wqkv, Wo);
    qkv_gemm<<<dim3(192, 32), 256, 0, stream>>>(xT, Wqkv, bq, bk, bv, Q, K, Vt);
    flash_attn<<<dim3(16, 8, 32), 256, 0, stream>>>(Q, K, Vt, mask, Q);
    out_gemm<<<dim3(64, 32), 256, 0, stream>>>(Wo, Q, bo, out);
  } else {
    unsigned short* Q  = (unsigned short*)d_ws;
    unsigned short* K  = Q + (size_t)33554432;
    unsigned short* Vt = K + (size_t)33554432;
    qkv_proj_old<<<dim3(64, 32, 3), 256, 0, stream>>>(x, wq, wk, wv, bq, bk, bv, Q, K, Vt);
    flash_attn<<<dim3(16, 8, 32), 256, 0, stream>>>(Q, K, Vt, mask, Q);
    out_proj_old<<<dim3(64, 32), 256, 0, stream>>>(Q, wo, bo, out);
  }
}

// Round 4
// 755.580 us; speedup vs baseline: 2.3297x; 1.0963x over previous
//
#include <hip/hip_runtime.h>
#include <hip/hip_bf16.h>

typedef __bf16 bf16_t;
typedef bf16_t bf16x8 __attribute__((ext_vector_type(8)));
typedef float f32x4 __attribute__((ext_vector_type(4)));

#define MFMA16(a, b, c) __builtin_amdgcn_mfma_f32_16x16x32_bf16(a, b, c, 0, 0, 0)
#define NEGV -1e30f

__device__ __forceinline__ unsigned short f2bf(float f) {
  union { float f; unsigned int u; } v; v.f = f;
  unsigned int r = v.u + 0x7FFFu + ((v.u >> 16) & 1u);
  return (unsigned short)(r >> 16);
}

__device__ __forceinline__ void gload16(const unsigned short* g, unsigned short* l) {
  __builtin_amdgcn_global_load_lds(
      (const __attribute__((address_space(1))) void*)g,
      (__attribute__((address_space(3))) void*)l, 16, 0, 0);
}

// ============ Kernel P1: x [B,D,L] fp32 -> xT [B,L,D] bf16 ============
__global__ __launch_bounds__(256) void x_transpose(
    const float* __restrict__ x, unsigned short* __restrict__ xT)
{
  const int b = blockIdx.z;
  const int l0 = blockIdx.x * 64, d0 = blockIdx.y * 64;
  __shared__ __align__(16) unsigned short T[64][68];
  const int tid = threadIdx.x;
  const int dl = tid >> 4, lc = (tid & 15) * 4;
#pragma unroll
  for (int rep = 0; rep < 4; ++rep) {
    int d = dl + rep * 16;
    float4 v = *reinterpret_cast<const float4*>(
        x + ((size_t)b * 1024 + d0 + d) * 1024 + l0 + lc);
    ushort4 u;
    u.x = f2bf(v.x); u.y = f2bf(v.y); u.z = f2bf(v.z); u.w = f2bf(v.w);
    *reinterpret_cast<ushort4*>(&T[d][lc]) = u;
  }
  __syncthreads();
  const int dbase = (tid & 15) * 4, lbase = (tid >> 4) * 4;
  ushort4 r0 = *reinterpret_cast<const ushort4*>(&T[dbase + 0][lbase]);
  ushort4 r1 = *reinterpret_cast<const ushort4*>(&T[dbase + 1][lbase]);
  ushort4 r2 = *reinterpret_cast<const ushort4*>(&T[dbase + 2][lbase]);
  ushort4 r3 = *reinterpret_cast<const ushort4*>(&T[dbase + 3][lbase]);
  ushort4 w0 = {r0.x, r1.x, r2.x, r3.x};
  ushort4 w1 = {r0.y, r1.y, r2.y, r3.y};
  ushort4 w2 = {r0.z, r1.z, r2.z, r3.z};
  ushort4 w3 = {r0.w, r1.w, r2.w, r3.w};
  unsigned short* op = xT + ((size_t)b * 1024 + l0 + lbase) * 1024 + d0 + dbase;
  *reinterpret_cast<ushort4*>(op) = w0;
  *reinterpret_cast<ushort4*>(op + 1024) = w1;
  *reinterpret_cast<ushort4*>(op + 2048) = w2;
  *reinterpret_cast<ushort4*>(op + 3072) = w3;
}

// ============ Kernel P2: weights fp32 -> bf16 (Wqkv concat + Wo) ============
__global__ __launch_bounds__(256) void w_convert(
    const float* __restrict__ wq, const float* __restrict__ wk,
    const float* __restrict__ wv, const float* __restrict__ wo,
    unsigned short* __restrict__ Wqkv, unsigned short* __restrict__ Wo)
{
  const int z = blockIdx.y;
  const float* src = (z == 0) ? wq : (z == 1) ? wk : (z == 2) ? wv : wo;
  unsigned short* dst = (z < 3) ? Wqkv + (size_t)z * 1048576 : Wo;
  size_t off = ((size_t)blockIdx.x * 256 + threadIdx.x) * 4;
  float4 v = *reinterpret_cast<const float4*>(src + off);
  ushort4 u = {f2bf(v.x), f2bf(v.y), f2bf(v.z), f2bf(v.w)};
  *reinterpret_cast<ushort4*>(dst + off) = u;
}

// ============ Kernel A: fused QKV GEMM (m97 structure) ============
__global__ __launch_bounds__(256) void qkv_gemm(
    const unsigned short* __restrict__ xT, const unsigned short* __restrict__ Wqkv,
    const float* __restrict__ bq, const float* __restrict__ bk, const float* __restrict__ bv,
    unsigned short* __restrict__ Q, unsigned short* __restrict__ K,
    unsigned short* __restrict__ Vt)
{
  const int tid = threadIdx.x;
  const int wave = tid >> 6, lane = tid & 63;
  const int lr = lane & 15, lg = lane >> 4;
  const int wr = wave >> 1, wc = wave & 1;
  const int mt = blockIdx.x & 7, nt = blockIdx.x >> 3;  // 8 x 24
  const int b = blockIdx.y;
  const int l0 = mt * 128, n0 = nt * 128;
  const unsigned short* Ap = xT + ((size_t)b << 20) + (size_t)l0 * 1024;
  const unsigned short* Bp = Wqkv + (size_t)n0 * 1024;

  __shared__ __align__(16) unsigned short lA[128 * 64];
  __shared__ __align__(16) unsigned short lB[128 * 64];

  f32x4 acc[4][4];
#pragma unroll
  for (int m = 0; m < 4; ++m)
#pragma unroll
    for (int n = 0; n < 4; ++n) acc[m][n] = (f32x4){0.f, 0.f, 0.f, 0.f};

  const int srow = tid >> 3, scol = (tid & 7) * 8;

  for (int k0 = 0; k0 < 1024; k0 += 64) {
#pragma unroll
    for (int i = 0; i < 4; ++i) {
      gload16(Ap + (size_t)(i * 32 + srow) * 1024 + k0 + scol, &lA[i * 2048 + tid * 8]);
      gload16(Bp + (size_t)(i * 32 + srow) * 1024 + k0 + scol, &lB[i * 2048 + tid * 8]);
    }
    __syncthreads();
    bf16x8 af[2][4], bfr[2][4];
#pragma unroll
    for (int kk = 0; kk < 2; ++kk) {
#pragma unroll
      for (int m = 0; m < 4; ++m)
        af[kk][m] = *reinterpret_cast<const bf16x8*>(
            &lA[(wr * 64 + m * 16 + lr) * 64 + kk * 32 + lg * 8]);
#pragma unroll
      for (int n = 0; n < 4; ++n)
        bfr[kk][n] = *reinterpret_cast<const bf16x8*>(
            &lB[(wc * 64 + n * 16 + lr) * 64 + kk * 32 + lg * 8]);
    }
#pragma unroll
    for (int kk = 0; kk < 2; ++kk)
#pragma unroll
      for (int m = 0; m < 4; ++m)
#pragma unroll
        for (int n = 0; n < 4; ++n)
          acc[m][n] = MFMA16(af[kk][m], bfr[kk][n], acc[m][n]);
    __syncthreads();
  }

  const int zi = n0 >> 10;
  const int h = (n0 & 1023) >> 7;
  const float* bias = (zi == 0) ? bq : (zi == 1) ? bk : bv;
  const size_t bhbase = ((size_t)b * 8 + h) * 131072;

  if (zi < 2) {
    unsigned short* op = ((zi == 0) ? Q : K) + bhbase;
#pragma unroll
    for (int n = 0; n < 4; ++n) {
      const int d = wc * 64 + n * 16 + lr;
      const float bs = bias[h * 128 + d];
#pragma unroll
      for (int m = 0; m < 4; ++m)
#pragma unroll
        for (int ii = 0; ii < 4; ++ii) {
          int l = l0 + wr * 64 + m * 16 + lg * 4 + ii;
          op[(size_t)l * 128 + d] = f2bf(acc[m][n][ii] + bs);
        }
    }
  } else {
#pragma unroll
    for (int n = 0; n < 4; ++n) {
      const int d = wc * 64 + n * 16 + lr;
      const float bs = bias[h * 128 + d];
#pragma unroll
      for (int m = 0; m < 4; ++m) {
        int l = l0 + wr * 64 + m * 16 + lg * 4;
        ushort4 u = {f2bf(acc[m][n][0] + bs), f2bf(acc[m][n][1] + bs),
                     f2bf(acc[m][n][2] + bs), f2bf(acc[m][n][3] + bs)};
        *reinterpret_cast<ushort4*>(&Vt[bhbase + (size_t)d * 1024 + l]) = u;
      }
    }
  }
}

// ============ Kernel C: output projection GEMM (m97 structure) ============
__global__ __launch_bounds__(256) void out_gemm(
    const unsigned short* __restrict__ Wo, const unsigned short* __restrict__ O,
    const float* __restrict__ bo, float* __restrict__ out)
{
  const int tid = threadIdx.x;
  const int wave = tid >> 6, lane = tid & 63;
  const int lr = lane & 15, lg = lane >> 4;
  const int wr = wave >> 1, wc = wave & 1;
  const int mt = blockIdx.x & 7, nt = blockIdx.x >> 3;
  const int b = blockIdx.y;
  const int d0 = mt * 128, l0 = nt * 128;
  const unsigned short* Ap = Wo + (size_t)d0 * 1024;

  __shared__ __align__(16) unsigned short lA[128 * 64];
  __shared__ __align__(16) unsigned short lB[128 * 64];

  f32x4 acc[4][4];
#pragma unroll
  for (int m = 0; m < 4; ++m)
#pragma unroll
    for (int n = 0; n < 4; ++n) acc[m][n] = (f32x4){0.f, 0.f, 0.f, 0.f};

  const int srow = tid >> 3, scol = (tid & 7) * 8;

  for (int k0 = 0; k0 < 1024; k0 += 64) {
    const unsigned short* Bp =
        O + (((size_t)b * 8 + (k0 >> 7)) * 1024 + l0) * 128 + (k0 & 64);
#pragma unroll
    for (int i = 0; i < 4; ++i) {
      gload16(Ap + (size_t)(i * 32 + srow) * 1024 + k0 + scol, &lA[i * 2048 + tid * 8]);
      gload16(Bp + (size_t)(i * 32 + srow) * 128 + scol, &lB[i * 2048 + tid * 8]);
    }
    __syncthreads();
    bf16x8 af[2][4], bfr[2][4];
#pragma unroll
    for (int kk = 0; kk < 2; ++kk) {
#pragma unroll
      for (int m = 0; m < 4; ++m)
        af[kk][m] = *reinterpret_cast<const bf16x8*>(
            &lA[(wr * 64 + m * 16 + lr) * 64 + kk * 32 + lg * 8]);
#pragma unroll
      for (int n = 0; n < 4; ++n)
        bfr[kk][n] = *reinterpret_cast<const bf16x8*>(
            &lB[(wc * 64 + n * 16 + lr) * 64 + kk * 32 + lg * 8]);
    }
#pragma unroll
    for (int kk = 0; kk < 2; ++kk)
#pragma unroll
      for (int m = 0; m < 4; ++m)
#pragma unroll
        for (int n = 0; n < 4; ++n)
          acc[m][n] = MFMA16(af[kk][m], bfr[kk][n], acc[m][n]);
    __syncthreads();
  }

#pragma unroll
  for (int m = 0; m < 4; ++m) {
#pragma unroll
    for (int ii = 0; ii < 4; ++ii) {
      int dr = d0 + wr * 64 + m * 16 + lg * 4 + ii;
      float bs = bo[dr];
      float* orow = out + ((size_t)b * 1024 + dr) * 1024 + l0 + wc * 64 + lr;
#pragma unroll
      for (int n = 0; n < 4; ++n)
        orow[n * 16] = acc[m][n][ii] + bs;
    }
  }
}

// ============ Kernel B: flash attention, swapped-QK^T lane-local softmax =====
// grid (16 qtiles, 8 heads, 32 batch); 4 waves x 16 q-rows.
// S^T = MFMA(K, Q): lane (lr,lg) holds S[key = n*16+lg*4+i][q = lr]
// -> softmax reduce is 15-op in-register tree + 2 shfl (xor16/32).
// exp2-domain (scale & penalty pre-multiplied by log2e), defer-max THR=8.
__global__ __launch_bounds__(256) void flash_attn(
    const unsigned short* __restrict__ Q, const unsigned short* __restrict__ Kb,
    const unsigned short* __restrict__ Vt, const int* __restrict__ mask,
    unsigned short* __restrict__ O)
{
  const int tid = threadIdx.x, wave = tid >> 6, lane = tid & 63;
  const int lr = lane & 15, lg = lane >> 4;
  const int qt = blockIdx.x, h = blockIdx.y, b = blockIdx.z;
  const size_t bh = (size_t)b * 8 + h;
  const unsigned short* Qp = Q + bh * 131072;
  const unsigned short* Kp = Kb + bh * 131072;
  const unsigned short* Vp = Vt + bh * 131072;
  unsigned short* Op = O + bh * 131072;
  const int q0 = qt * 64 + wave * 16;
  const float SC2 = 0.12751744f;        // (1/sqrt(128)) * log2(e)
  const float NEG2 = -1.442695e30f;     // -1e30 * log2(e)

  __shared__ __align__(16) unsigned short Kl[2][64 * 128];
  __shared__ __align__(16) unsigned short Vl[2][128 * 64];
  __shared__ __align__(16) unsigned short plds[4][16 * 72];
  __shared__ float pen[1024];

  {
    const int4 mv = *reinterpret_cast<const int4*>(mask + b * 1024 + tid * 4);
    float4 pv;
    pv.x = mv.x ? NEG2 : 0.f; pv.y = mv.y ? NEG2 : 0.f;
    pv.z = mv.z ? NEG2 : 0.f; pv.w = mv.w ? NEG2 : 0.f;
    *reinterpret_cast<float4*>(&pen[tid * 4]) = pv;
  }

  unsigned short* myP = plds[wave];

  bf16x8 aq[4];
#pragma unroll
  for (int c = 0; c < 4; ++c)
    aq[c] = *reinterpret_cast<const bf16x8*>(&Qp[(size_t)(q0 + lr) * 128 + c * 32 + lg * 8]);

  const int ks_row = (tid >> 4);
  const int ks_cb0 = (tid & 15) * 16;
  const int vs_row = (tid >> 3);
  const int vs_cb0 = (tid & 7) * 16;

#define STAGE(bufi, ktv)                                                        \
  {                                                                             \
    _Pragma("unroll")                                                           \
    for (int i = 0; i < 4; ++i) {                                               \
      int krow = i * 16 + ks_row;                                               \
      int kcb = ks_cb0 ^ ((krow & 7) << 4);                                     \
      gload16(Kp + (size_t)((ktv) + krow) * 128 + (kcb >> 1),                   \
              &Kl[bufi][i * 2048 + wave * 512]);                                \
      int vrow = i * 32 + vs_row;                                               \
      int vcb = vs_cb0 ^ ((vrow & 7) << 4);                                     \
      gload16(Vp + (size_t)vrow * 1024 + (ktv) + (vcb >> 1),                    \
              &Vl[bufi][i * 2048 + wave * 512]);                                \
    }                                                                           \
  }

  f32x4 oacc[8];
#pragma unroll
  for (int dt = 0; dt < 8; ++dt) oacc[dt] = (f32x4){0.f, 0.f, 0.f, 0.f};
  float mrun = -3.0e38f;  // running max (log2 units) for q = lr
  float lrun = 0.f;       // running denom for q = lr

  STAGE(0, 0);
  __syncthreads();

  int cur = 0;
  for (int t = 0; t < 16; ++t) {
    const int kt = t * 64;
    if (t < 15) STAGE(cur ^ 1, kt + 64);

    // ---- S^T = K Q (swapped operands; same LDS reads as before) ----
    f32x4 s[4];
    __builtin_amdgcn_s_setprio(1);
#pragma unroll
    for (int n = 0; n < 4; ++n) {
      f32x4 a = (f32x4){0.f, 0.f, 0.f, 0.f};
      const int krow = n * 16 + lr;
      const int rsw = (krow & 7) << 4;
#pragma unroll
      for (int c = 0; c < 4; ++c) {
        bf16x8 bk = *reinterpret_cast<const bf16x8*>(
            &Kl[cur][krow * 128 + (((c * 64 + lg * 16) ^ rsw) >> 1)]);
        a = MFMA16(bk, aq[c], a);  // A = K-rows, B = Q -> C[key][q]
      }
      s[n] = a;
    }
    __builtin_amdgcn_s_setprio(0);

    // ---- scale + mask (key = kt + n*16 + lg*4 + i) ----
#pragma unroll
    for (int n = 0; n < 4; ++n) {
      f32x4 pv = *reinterpret_cast<const f32x4*>(&pen[kt + n * 16 + lg * 4]);
#pragma unroll
      for (int i = 0; i < 4; ++i) s[n][i] = s[n][i] * SC2 + pv[i];
    }

    // ---- lane-local max tree + 2-shfl cross-group reduce ----
    float mn[4];
#pragma unroll
    for (int n = 0; n < 4; ++n)
      mn[n] = fmaxf(fmaxf(s[n][0], s[n][1]), fmaxf(s[n][2], s[n][3]));
    float mx = fmaxf(fmaxf(mn[0], mn[1]), fmaxf(mn[2], mn[3]));
    mx = fmaxf(mx, __shfl_xor(mx, 16));
    mx = fmaxf(mx, __shfl_xor(mx, 32));

    // ---- defer-max (T13): rescale only when max grew materially ----
    if (!__all(mx <= mrun + 8.0f)) {
      float mnew = fmaxf(mrun, mx);
      float scq = __builtin_amdgcn_exp2f(mrun - mnew);  // for q = lr
      mrun = mnew;
      lrun *= scq;
#pragma unroll
      for (int i = 0; i < 4; ++i) {
        float sco = __shfl(scq, lg * 4 + i);  // for q = lg*4+i (oacc rows)
#pragma unroll
        for (int dt = 0; dt < 8; ++dt) oacc[dt][i] *= sco;
      }
    }

    // ---- p = exp2(s - mrun); lane-local sum tree + 2 shfl ----
    float p[4][4], lsn[4];
#pragma unroll
    for (int n = 0; n < 4; ++n) {
#pragma unroll
      for (int i = 0; i < 4; ++i)
        p[n][i] = __builtin_amdgcn_exp2f(s[n][i] - mrun);
      lsn[n] = (p[n][0] + p[n][1]) + (p[n][2] + p[n][3]);
    }
    float ls = (lsn[0] + lsn[1]) + (lsn[2] + lsn[3]);
    ls += __shfl_xor(ls, 16);
    ls += __shfl_xor(ls, 32);
    lrun += ls;

    // ---- pack P -> LDS row q=lr (packed b32 writes), read A-frags ----
#pragma unroll
    for (int n = 0; n < 4; ++n)
#pragma unroll
      for (int t2 = 0; t2 < 2; ++t2) {
        unsigned int u;
        asm("v_cvt_pk_bf16_f32 %0, %1, %2"
            : "=v"(u) : "v"(p[n][2 * t2]), "v"(p[n][2 * t2 + 1]));
        *reinterpret_cast<unsigned int*>(
            &myP[lr * 72 + n * 16 + lg * 4 + t2 * 2]) = u;
      }
    bf16x8 pa0 = *reinterpret_cast<const bf16x8*>(&myP[lr * 72 + lg * 8]);
    bf16x8 pa1 = *reinterpret_cast<const bf16x8*>(&myP[lr * 72 + 32 + lg * 8]);

    // ---- O += P V ----
    __builtin_amdgcn_s_setprio(1);
#pragma unroll
    for (int dt = 0; dt < 8; ++dt) {
      const int vrow = dt * 16 + lr;
      const int rsw = (vrow & 7) << 4;
      bf16x8 bv0 = *reinterpret_cast<const bf16x8*>(
          &Vl[cur][vrow * 64 + (((lg * 16) ^ rsw) >> 1)]);
      bf16x8 bv1 = *reinterpret_cast<const bf16x8*>(
          &Vl[cur][vrow * 64 + (((64 + lg * 16) ^ rsw) >> 1)]);
      oacc[dt] = MFMA16(pa0, bv0, oacc[dt]);
      oacc[dt] = MFMA16(pa1, bv1, oacc[dt]);
    }
    __builtin_amdgcn_s_setprio(0);

    __syncthreads();
    cur ^= 1;
  }

  // epilogue: oacc rows are q = lg*4+i; stats live in lanes lr = q
  float linv[4];
#pragma unroll
  for (int i = 0; i < 4; ++i) {
    float lq = __shfl(lrun, lg * 4 + i);
    linv[i] = 1.0f / lq;
  }
#pragma unroll
  for (int dt = 0; dt < 8; ++dt)
#pragma unroll
    for (int i = 0; i < 4; ++i)
      Op[(size_t)(q0 + lg * 4 + i) * 128 + dt * 16 + lr] = f2bf(oacc[dt][i] * linv[i]);
}

// ============ Fallback kernels (round-2, 192 MiB workspace) ============
__global__ __launch_bounds__(256) void qkv_proj_old(
    const float* __restrict__ x,
    const float* __restrict__ wq, const float* __restrict__ wk, const float* __restrict__ wv,
    const float* __restrict__ bq, const float* __restrict__ bk, const float* __restrict__ bv,
    unsigned short* __restrict__ Q, unsigned short* __restrict__ K, unsigned short* __restrict__ Vt)
{
  const int tid = threadIdx.x;
  const int wave = tid >> 6, lane = tid & 63;
  const int lr = lane & 15, lg = lane >> 4;
  const int wr = wave >> 1, wc = wave & 1;
  const int mt = blockIdx.x & 7, nt = blockIdx.x >> 3;
  const int b = blockIdx.y, z = blockIdx.z;
  const int l0 = mt * 128, i0 = nt * 128;
  const float* w    = (z == 0) ? wq : (z == 1) ? wk : wv;
  const float* bias = (z == 0) ? bq : (z == 1) ? bk : bv;
  unsigned short* outp = (z == 0) ? Q : (z == 1) ? K : Vt;

  __shared__ __align__(16) unsigned short lA[128 * 40];
  __shared__ __align__(16) unsigned short lB[128 * 40];

  f32x4 acc[4][4];
#pragma unroll
  for (int m = 0; m < 4; ++m)
#pragma unroll
    for (int n = 0; n < 4; ++n) acc[m][n] = (f32x4){0.f, 0.f, 0.f, 0.f};

  const int ad = tid >> 3, aj = tid & 7;
  const int br = tid >> 1, bh2 = tid & 1;

  for (int k0 = 0; k0 < 1024; k0 += 32) {
    const float* xp = x + ((size_t)b * 1024 + k0 + ad) * 1024 + l0;
#pragma unroll
    for (int rep = 0; rep < 4; ++rep) {
      float4 v = *reinterpret_cast<const float4*>(xp + aj * 4 + rep * 32);
      int lb = aj * 4 + rep * 32;
      lA[(lb + 0) * 40 + ad] = f2bf(v.x);
      lA[(lb + 1) * 40 + ad] = f2bf(v.y);
      lA[(lb + 2) * 40 + ad] = f2bf(v.z);
      lA[(lb + 3) * 40 + ad] = f2bf(v.w);
    }
    const float* wp = w + (size_t)(i0 + br) * 1024 + k0 + bh2 * 16;
#pragma unroll
    for (int rep = 0; rep < 4; ++rep) {
      float4 v = *reinterpret_cast<const float4*>(wp + rep * 4);
      int cb = br * 40 + bh2 * 16 + rep * 4;
      lB[cb + 0] = f2bf(v.x); lB[cb + 1] = f2bf(v.y);
      lB[cb + 2] = f2bf(v.z); lB[cb + 3] = f2bf(v.w);
    }
    __syncthreads();
    bf16x8 af[4], bfr[4];
#pragma unroll
    for (int m = 0; m < 4; ++m)
      af[m] = *reinterpret_cast<const bf16x8*>(&lA[(wr * 64 + m * 16 + lr) * 40 + lg * 8]);
#pragma unroll
    for (int n = 0; n < 4; ++n)
      bfr[n] = *reinterpret_cast<const bf16x8*>(&lB[(wc * 64 + n * 16 + lr) * 40 + lg * 8]);
#pragma unroll
    for (int m = 0; m < 4; ++m)
#pragma unroll
      for (int n = 0; n < 4; ++n)
        acc[m][n] = MFMA16(af[m], bfr[n], acc[m][n]);
    __syncthreads();
  }
#pragma unroll
  for (int n = 0; n < 4; ++n) {
    int col = i0 + wc * 64 + n * 16 + lr;
    float bs = bias[col];
    int h = col >> 7, d = col & 127;
#pragma unroll
    for (int m = 0; m < 4; ++m) {
#pragma unroll
      for (int ii = 0; ii < 4; ++ii) {
        int row = l0 + wr * 64 + m * 16 + lg * 4 + ii;
        unsigned short val = f2bf(acc[m][n][ii] + bs);
        if (z < 2)
          outp[(((size_t)b * 8 + h) * 1024 + row) * 128 + d] = val;
        else
          outp[(((size_t)b * 8 + h) * 128 + d) * 1024 + row] = val;
      }
    }
  }
}

__global__ __launch_bounds__(256) void out_proj_old(
    const unsigned short* __restrict__ Obuf, const float* __restrict__ wo,
    const float* __restrict__ bo, float* __restrict__ out)
{
  const int tid = threadIdx.x, wave = tid >> 6, lane = tid & 63;
  const int lr = lane & 15, lg = lane >> 4;
  const int wr = wave >> 1, wc = wave & 1;
  const int mt = blockIdx.x & 7, nt = blockIdx.x >> 3;
  const int b = blockIdx.y;
  const int d0 = mt * 128, l0 = nt * 128;

  __shared__ __align__(16) unsigned short lA[128 * 40];
  __shared__ __align__(16) unsigned short lB[128 * 40];

  f32x4 acc[4][4];
#pragma unroll
  for (int m = 0; m < 4; ++m)
#pragma unroll
    for (int n = 0; n < 4; ++n) acc[m][n] = (f32x4){0.f, 0.f, 0.f, 0.f};

  const int ar = tid >> 1, ah = tid & 1;

  for (int k0 = 0; k0 < 1024; k0 += 32) {
    const float* wp = wo + (size_t)(d0 + ar) * 1024 + k0 + ah * 16;
#pragma unroll
    for (int rep = 0; rep < 4; ++rep) {
      float4 v = *reinterpret_cast<const float4*>(wp + rep * 4);
      int cb = ar * 40 + ah * 16 + rep * 4;
      lA[cb + 0] = f2bf(v.x); lA[cb + 1] = f2bf(v.y);
      lA[cb + 2] = f2bf(v.z); lA[cb + 3] = f2bf(v.w);
    }
    {
      int head = k0 >> 7, dk = (k0 & 127) + ah * 16;
      const unsigned short* op =
          Obuf + (((size_t)b * 8 + head) * 1024 + l0 + ar) * 128 + dk;
#pragma unroll
      for (int rep = 0; rep < 2; ++rep) {
        bf16x8 v = *reinterpret_cast<const bf16x8*>(op + rep * 8);
        *reinterpret_cast<bf16x8*>(&lB[ar * 40 + ah * 16 + rep * 8]) = v;
      }
    }
    __syncthreads();
    bf16x8 af[4], bfr[4];
#pragma unroll
    for (int m = 0; m < 4; ++m)
      af[m] = *reinterpret_cast<const bf16x8*>(&lA[(wr * 64 + m * 16 + lr) * 40 + lg * 8]);
#pragma unroll
    for (int n = 0; n < 4; ++n)
      bfr[n] = *reinterpret_cast<const bf16x8*>(&lB[(wc * 64 + n * 16 + lr) * 40 + lg * 8]);
#pragma unroll
    for (int m = 0; m < 4; ++m)
#pragma unroll
      for (int n = 0; n < 4; ++n)
        acc[m][n] = MFMA16(af[m], bfr[n], acc[m][n]);
    __syncthreads();
  }
#pragma unroll
  for (int m = 0; m < 4; ++m) {
#pragma unroll
    for (int ii = 0; ii < 4; ++ii) {
      int dr = d0 + wr * 64 + m * 16 + lg * 4 + ii;
      float bs = bo[dr];
      float* orow = out + ((size_t)b * 1024 + dr) * 1024 + l0 + wc * 64 + lr;
#pragma unroll
      for (int n = 0; n < 4; ++n)
        orow[n * 16] = acc[m][n][ii] + bs;
    }
  }
}

extern "C" void kernel_launch(void* const* d_in, const int* in_sizes, int n_in,
                              void* d_out, int out_size, void* d_ws, size_t ws_size,
                              hipStream_t stream) {
  const float* x  = (const float*)d_in[0];
  const int* mask = (const int*)d_in[1];
  const float* wq = (const float*)d_in[2];
  const float* bq = (const float*)d_in[3];
  const float* wk = (const float*)d_in[4];
  const float* bk = (const float*)d_in[5];
  const float* wv = (const float*)d_in[6];
  const float* bv = (const float*)d_in[7];
  const float* wo = (const float*)d_in[8];
  const float* bo = (const float*)d_in[9];
  float* out = (float*)d_out;

  const size_t MB64 = (size_t)64 << 20;
  const size_t NEED = (size_t)264 << 20;

  if (ws_size >= NEED) {
    unsigned short* xT   = (unsigned short*)d_ws;
    unsigned short* Q    = (unsigned short*)((char*)d_ws + MB64);
    unsigned short* K    = (unsigned short*)((char*)d_ws + 2 * MB64);
    unsigned short* Vt   = (unsigned short*)((char*)d_ws + 3 * MB64);
    unsigned short* Wqkv = (unsigned short*)((char*)d_ws + 4 * MB64);
    unsigned short* Wo   = Wqkv + (size_t)3 * 1048576;

    x_transpose<<<dim3(16, 16, 32), 256, 0, stream>>>(x, xT);
    w_convert<<<dim3(1024, 4), 256, 0, stream>>>(wq, wk, wv, wo, Wqkv, Wo);
    qkv_gemm<<<dim3(192, 32), 256, 0, stream>>>(xT, Wqkv, bq, bk, bv, Q, K, Vt);
    flash_attn<<<dim3(16, 8, 32), 256, 0, stream>>>(Q, K, Vt, mask, Q);
    out_gemm<<<dim3(64, 32), 256, 0, stream>>>(Wo, Q, bo, out);
  } else {
    unsigned short* Q  = (unsigned short*)d_ws;
    unsigned short* K  = Q + (size_t)33554432;
    unsigned short* Vt = K + (size_t)33554432;
    qkv_proj_old<<<dim3(64, 32, 3), 256, 0, stream>>>(x, wq, wk, wv, bq, bk, bv, Q, K, Vt);
    flash_attn<<<dim3(16, 8, 32), 256, 0, stream>>>(Q, K, Vt, mask, Q);
    out_proj_old<<<dim3(64, 32), 256, 0, stream>>>(Q, wo, bo, out);
  }
}

// Round 5
// 660.589 us; speedup vs baseline: 2.6648x; 1.1438x over previous
//
#include <hip/hip_runtime.h>
#include <hip/hip_bf16.h>

typedef __bf16 bf16_t;
typedef bf16_t bf16x8 __attribute__((ext_vector_type(8)));
typedef float f32x4 __attribute__((ext_vector_type(4)));

#define MFMA16(a, b, c) __builtin_amdgcn_mfma_f32_16x16x32_bf16(a, b, c, 0, 0, 0)
#define NEGV -1e30f

__device__ __forceinline__ unsigned short f2bf(float f) {
  union { float f; unsigned int u; } v; v.f = f;
  unsigned int r = v.u + 0x7FFFu + ((v.u >> 16) & 1u);
  return (unsigned short)(r >> 16);
}

__device__ __forceinline__ void gload16(const unsigned short* g, unsigned short* l) {
  __builtin_amdgcn_global_load_lds(
      (const __attribute__((address_space(1))) void*)g,
      (__attribute__((address_space(3))) void*)l, 16, 0, 0);
}

// ============ Kernel P1: x [B,D,L] fp32 -> xT [B,L,D] bf16 ============
__global__ __launch_bounds__(256) void x_transpose(
    const float* __restrict__ x, unsigned short* __restrict__ xT)
{
  const int b = blockIdx.z;
  const int l0 = blockIdx.x * 64, d0 = blockIdx.y * 64;
  __shared__ __align__(16) unsigned short T[64][68];
  const int tid = threadIdx.x;
  const int dl = tid >> 4, lc = (tid & 15) * 4;
#pragma unroll
  for (int rep = 0; rep < 4; ++rep) {
    int d = dl + rep * 16;
    float4 v = *reinterpret_cast<const float4*>(
        x + ((size_t)b * 1024 + d0 + d) * 1024 + l0 + lc);
    ushort4 u;
    u.x = f2bf(v.x); u.y = f2bf(v.y); u.z = f2bf(v.z); u.w = f2bf(v.w);
    *reinterpret_cast<ushort4*>(&T[d][lc]) = u;
  }
  __syncthreads();
  const int dbase = (tid & 15) * 4, lbase = (tid >> 4) * 4;
  ushort4 r0 = *reinterpret_cast<const ushort4*>(&T[dbase + 0][lbase]);
  ushort4 r1 = *reinterpret_cast<const ushort4*>(&T[dbase + 1][lbase]);
  ushort4 r2 = *reinterpret_cast<const ushort4*>(&T[dbase + 2][lbase]);
  ushort4 r3 = *reinterpret_cast<const ushort4*>(&T[dbase + 3][lbase]);
  ushort4 w0 = {r0.x, r1.x, r2.x, r3.x};
  ushort4 w1 = {r0.y, r1.y, r2.y, r3.y};
  ushort4 w2 = {r0.z, r1.z, r2.z, r3.z};
  ushort4 w3 = {r0.w, r1.w, r2.w, r3.w};
  unsigned short* op = xT + ((size_t)b * 1024 + l0 + lbase) * 1024 + d0 + dbase;
  *reinterpret_cast<ushort4*>(op) = w0;
  *reinterpret_cast<ushort4*>(op + 1024) = w1;
  *reinterpret_cast<ushort4*>(op + 2048) = w2;
  *reinterpret_cast<ushort4*>(op + 3072) = w3;
}

// ============ Kernel P2: weights fp32 -> bf16 (Wqkv concat + Wo) ============
__global__ __launch_bounds__(256) void w_convert(
    const float* __restrict__ wq, const float* __restrict__ wk,
    const float* __restrict__ wv, const float* __restrict__ wo,
    unsigned short* __restrict__ Wqkv, unsigned short* __restrict__ Wo)
{
  const int z = blockIdx.y;
  const float* src = (z == 0) ? wq : (z == 1) ? wk : (z == 2) ? wv : wo;
  unsigned short* dst = (z < 3) ? Wqkv + (size_t)z * 1048576 : Wo;
  size_t off = ((size_t)blockIdx.x * 256 + threadIdx.x) * 4;
  float4 v = *reinterpret_cast<const float4*>(src + off);
  ushort4 u = {f2bf(v.x), f2bf(v.y), f2bf(v.z), f2bf(v.w)};
  *reinterpret_cast<ushort4*>(dst + off) = u;
}

// ============ Kernel A: fused QKV GEMM — 256^2 / BK64, 8-phase counted-vmcnt ==
// One flat GEMM: C[32768, 3072] = xT . Wqkv^T. 512 thr = 8 waves (2M x 4N).
// LDS: 2 K-tile buffers x 4 K-split half-tiles (A-K0, A-K1, B-K0, B-K1),
// 64-B rows (bank-uniform ds_read_b128, no swizzle needed).
// Staging: 1 half-tile/phase; vmcnt(10) at odd-phase ends only.
__global__ __launch_bounds__(512, 2) void qkv_gemm8(
    const unsigned short* __restrict__ xT, const unsigned short* __restrict__ Wqkv,
    const float* __restrict__ bq, const float* __restrict__ bk, const float* __restrict__ bv,
    unsigned short* __restrict__ Q, unsigned short* __restrict__ K,
    unsigned short* __restrict__ Vt)
{
  __shared__ __align__(16) unsigned short lds[2][4][8192];  // 128 KiB

  const int tid = threadIdx.x;
  const int wave = tid >> 6, lane = tid & 63;
  const int lr = lane & 15, lg = lane >> 4;
  const int wr = wave >> 2, wc = wave & 3;

  const int bid = blockIdx.x;
  const int swz = (bid & 7) * 192 + (bid >> 3);  // 1536 % 8 == 0: bijective
  const int mt = swz / 12, nt = swz % 12;
  const int m0 = mt * 256, n0 = nt * 256;

  const unsigned short* Ag = xT + (size_t)m0 * 1024;
  const unsigned short* Bg = Wqkv + (size_t)n0 * 1024;

  const int srow = tid >> 2;          // 0..127
  const int schk = (tid & 3) * 8;     // k-elem offset within 32-wide half

  // region: 0=A k[0,32) 1=A k[32,64) 2=B k[0,32) 3=B k[32,64)
#define STAGE_HT(BUF, REG, TI)                                                 \
  {                                                                            \
    const int kt_ = ((TI) < 16 ? (TI) : 15) * 64 + (((REG)&1) * 32) + schk;    \
    const unsigned short* gp_ = (((REG) < 2) ? Ag : Bg);                       \
    _Pragma("unroll")                                                          \
    for (int j_ = 0; j_ < 2; ++j_)                                             \
      gload16(gp_ + (size_t)(j_ * 128 + srow) * 1024 + kt_,                    \
              &lds[BUF][REG][j_ * 4096 + tid * 8]);                            \
  }

#define LDA(BUF, KK, MH, AR)                                                   \
  _Pragma("unroll")                                                            \
  for (int mi_ = 0; mi_ < 4; ++mi_)                                            \
    AR[mi_] = *reinterpret_cast<const bf16x8*>(                                \
        &lds[BUF][KK][(wr * 128 + (MH)*64 + mi_ * 16 + lr) * 32 + lg * 8]);

#define LDB(BUF, KK, BR)                                                       \
  _Pragma("unroll")                                                            \
  for (int n_ = 0; n_ < 4; ++n_)                                               \
    BR[n_] = *reinterpret_cast<const bf16x8*>(                                 \
        &lds[BUF][2 + (KK)][(wc * 64 + n_ * 16 + lr) * 32 + lg * 8]);

#define MM(AR, BR, MH)                                                         \
  __builtin_amdgcn_s_setprio(1);                                               \
  _Pragma("unroll")                                                            \
  for (int mi_ = 0; mi_ < 4; ++mi_)                                            \
    _Pragma("unroll")                                                          \
    for (int n_ = 0; n_ < 4; ++n_)                                             \
      acc[(MH)*4 + mi_][n_] = MFMA16(AR[mi_], BR[n_], acc[(MH)*4 + mi_][n_]);  \
  __builtin_amdgcn_s_setprio(0);

#define BAR()                                                                  \
  {                                                                            \
    asm volatile("" ::: "memory");                                             \
    __builtin_amdgcn_s_barrier();                                              \
    asm volatile("" ::: "memory");                                             \
  }
#define VMW() asm volatile("s_waitcnt vmcnt(10)" ::: "memory")

  f32x4 acc[8][4];
#pragma unroll
  for (int m = 0; m < 8; ++m)
#pragma unroll
    for (int n = 0; n < 4; ++n) acc[m][n] = (f32x4){0.f, 0.f, 0.f, 0.f};

  // prologue: tile0 {BK0, AK0, BK1, AK1}, tile1 {BK0, AK0, BK1}
  STAGE_HT(0, 2, 0); STAGE_HT(0, 0, 0); STAGE_HT(0, 3, 0); STAGE_HT(0, 1, 0);
  STAGE_HT(1, 2, 1); STAGE_HT(1, 0, 1); STAGE_HT(1, 3, 1);
  VMW();  // 14 issued; oldest 4 (BK0/AK0 of tile0) complete
  BAR();

  for (int it = 0; it < 8; ++it) {
    const int T = 2 * it;
    bf16x8 a0[4], a1[4], b0[4], b1[4];
    // ---- tile T (buf0) ----
    // p0: (kk0, mh0) | stage A-K1(T+1) -> buf1
    LDB(0, 0, b0); LDA(0, 0, 0, a0);
    STAGE_HT(1, 1, T + 1);
    BAR();
    MM(a0, b0, 0);
    BAR();
    // p1: (kk0, mh1) | stage B-K0(T+2) -> buf0
    LDA(0, 0, 1, a1);
    STAGE_HT(0, 2, T + 2);
    BAR();
    MM(a1, b0, 1);
    VMW(); BAR();
    // p2: (kk1, mh0) | stage A-K0(T+2) -> buf0
    LDB(0, 1, b1); LDA(0, 1, 0, a0);
    STAGE_HT(0, 0, T + 2);
    BAR();
    MM(a0, b1, 0);
    BAR();
    // p3: (kk1, mh1) | stage B-K1(T+2) -> buf0
    LDA(0, 1, 1, a1);
    STAGE_HT(0, 3, T + 2);
    BAR();
    MM(a1, b1, 1);
    VMW(); BAR();
    // ---- tile T+1 (buf1) ----
    // p4: (kk0, mh0) | stage A-K1(T+2) -> buf0
    LDB(1, 0, b0); LDA(1, 0, 0, a0);
    STAGE_HT(0, 1, T + 2);
    BAR();
    MM(a0, b0, 0);
    BAR();
    // p5: (kk0, mh1) | stage B-K0(T+3) -> buf1
    LDA(1, 0, 1, a1);
    STAGE_HT(1, 2, T + 3);
    BAR();
    MM(a1, b0, 1);
    VMW(); BAR();
    // p6: (kk1, mh0) | stage A-K0(T+3) -> buf1
    LDB(1, 1, b1); LDA(1, 1, 0, a0);
    STAGE_HT(1, 0, T + 3);
    BAR();
    MM(a0, b1, 0);
    BAR();
    // p7: (kk1, mh1) | stage B-K1(T+3) -> buf1
    LDA(1, 1, 1, a1);
    STAGE_HT(1, 3, T + 3);
    BAR();
    MM(a1, b1, 1);
    VMW(); BAR();
  }

  // ---- epilogue: route to Q / K / Vt ----
  const int zi = n0 >> 10;                // whole 256-tile in one of q/k/v
  const float* bias = (zi == 0) ? bq : (zi == 1) ? bk : bv;
  const int b = m0 >> 10;                 // whole M-tile in one batch
  const int lbase = (m0 & 1023) + wr * 128;

  if (zi < 2) {
    unsigned short* op = ((zi == 0) ? Q : K);
#pragma unroll
    for (int n = 0; n < 4; ++n) {
      const int col = (n0 & 1023) + wc * 64 + n * 16 + lr;
      const int h = col >> 7, d = col & 127;
      const float bs = bias[col];
      unsigned short* hp = op + ((size_t)b * 8 + h) * 131072 + d;
#pragma unroll
      for (int m = 0; m < 8; ++m)
#pragma unroll
        for (int ii = 0; ii < 4; ++ii) {
          int l = lbase + m * 16 + lg * 4 + ii;
          hp[(size_t)l * 128] = f2bf(acc[m][n][ii] + bs);
        }
    }
  } else {
#pragma unroll
    for (int n = 0; n < 4; ++n) {
      const int col = (n0 & 1023) + wc * 64 + n * 16 + lr;
      const int h = col >> 7, d = col & 127;
      const float bs = bias[col];
      unsigned short* hp = Vt + ((size_t)b * 8 + h) * 131072 + (size_t)d * 1024;
#pragma unroll
      for (int m = 0; m < 8; ++m) {
        int l = lbase + m * 16 + lg * 4;
        ushort4 u = {f2bf(acc[m][n][0] + bs), f2bf(acc[m][n][1] + bs),
                     f2bf(acc[m][n][2] + bs), f2bf(acc[m][n][3] + bs)};
        *reinterpret_cast<ushort4*>(&hp[l]) = u;
      }
    }
  }
#undef STAGE_HT
#undef LDA
#undef LDB
#undef MM
#undef BAR
#undef VMW
}

// ============ Kernel C: output projection GEMM (m97 structure) ============
__global__ __launch_bounds__(256) void out_gemm(
    const unsigned short* __restrict__ Wo, const unsigned short* __restrict__ O,
    const float* __restrict__ bo, float* __restrict__ out)
{
  const int tid = threadIdx.x;
  const int wave = tid >> 6, lane = tid & 63;
  const int lr = lane & 15, lg = lane >> 4;
  const int wr = wave >> 1, wc = wave & 1;
  const int mt = blockIdx.x & 7, nt = blockIdx.x >> 3;
  const int b = blockIdx.y;
  const int d0 = mt * 128, l0 = nt * 128;
  const unsigned short* Ap = Wo + (size_t)d0 * 1024;

  __shared__ __align__(16) unsigned short lA[128 * 64];
  __shared__ __align__(16) unsigned short lB[128 * 64];

  f32x4 acc[4][4];
#pragma unroll
  for (int m = 0; m < 4; ++m)
#pragma unroll
    for (int n = 0; n < 4; ++n) acc[m][n] = (f32x4){0.f, 0.f, 0.f, 0.f};

  const int srow = tid >> 3, scol = (tid & 7) * 8;

  for (int k0 = 0; k0 < 1024; k0 += 64) {
    const unsigned short* Bp =
        O + (((size_t)b * 8 + (k0 >> 7)) * 1024 + l0) * 128 + (k0 & 64);
#pragma unroll
    for (int i = 0; i < 4; ++i) {
      gload16(Ap + (size_t)(i * 32 + srow) * 1024 + k0 + scol, &lA[i * 2048 + tid * 8]);
      gload16(Bp + (size_t)(i * 32 + srow) * 128 + scol, &lB[i * 2048 + tid * 8]);
    }
    __syncthreads();
    bf16x8 af[2][4], bfr[2][4];
#pragma unroll
    for (int kk = 0; kk < 2; ++kk) {
#pragma unroll
      for (int m = 0; m < 4; ++m)
        af[kk][m] = *reinterpret_cast<const bf16x8*>(
            &lA[(wr * 64 + m * 16 + lr) * 64 + kk * 32 + lg * 8]);
#pragma unroll
      for (int n = 0; n < 4; ++n)
        bfr[kk][n] = *reinterpret_cast<const bf16x8*>(
            &lB[(wc * 64 + n * 16 + lr) * 64 + kk * 32 + lg * 8]);
    }
#pragma unroll
    for (int kk = 0; kk < 2; ++kk)
#pragma unroll
      for (int m = 0; m < 4; ++m)
#pragma unroll
        for (int n = 0; n < 4; ++n)
          acc[m][n] = MFMA16(af[kk][m], bfr[kk][n], acc[m][n]);
    __syncthreads();
  }

#pragma unroll
  for (int m = 0; m < 4; ++m) {
#pragma unroll
    for (int ii = 0; ii < 4; ++ii) {
      int dr = d0 + wr * 64 + m * 16 + lg * 4 + ii;
      float bs = bo[dr];
      float* orow = out + ((size_t)b * 1024 + dr) * 1024 + l0 + wc * 64 + lr;
#pragma unroll
      for (int n = 0; n < 4; ++n)
        orow[n * 16] = acc[m][n][ii] + bs;
    }
  }
}

// ============ Kernel B: flash attention, swapped-QK^T lane-local softmax =====
__global__ __launch_bounds__(256) void flash_attn(
    const unsigned short* __restrict__ Q, const unsigned short* __restrict__ Kb,
    const unsigned short* __restrict__ Vt, const int* __restrict__ mask,
    unsigned short* __restrict__ O)
{
  const int tid = threadIdx.x, wave = tid >> 6, lane = tid & 63;
  const int lr = lane & 15, lg = lane >> 4;
  const int qt = blockIdx.x, h = blockIdx.y, b = blockIdx.z;
  const size_t bh = (size_t)b * 8 + h;
  const unsigned short* Qp = Q + bh * 131072;
  const unsigned short* Kp = Kb + bh * 131072;
  const unsigned short* Vp = Vt + bh * 131072;
  unsigned short* Op = O + bh * 131072;
  const int q0 = qt * 64 + wave * 16;
  const float SC2 = 0.12751744f;        // (1/sqrt(128)) * log2(e)
  const float NEG2 = -1.442695e30f;     // -1e30 * log2(e)

  __shared__ __align__(16) unsigned short Kl[2][64 * 128];
  __shared__ __align__(16) unsigned short Vl[2][128 * 64];
  __shared__ __align__(16) unsigned short plds[4][16 * 72];
  __shared__ float pen[1024];

  {
    const int4 mv = *reinterpret_cast<const int4*>(mask + b * 1024 + tid * 4);
    float4 pv;
    pv.x = mv.x ? NEG2 : 0.f; pv.y = mv.y ? NEG2 : 0.f;
    pv.z = mv.z ? NEG2 : 0.f; pv.w = mv.w ? NEG2 : 0.f;
    *reinterpret_cast<float4*>(&pen[tid * 4]) = pv;
  }

  unsigned short* myP = plds[wave];

  bf16x8 aq[4];
#pragma unroll
  for (int c = 0; c < 4; ++c)
    aq[c] = *reinterpret_cast<const bf16x8*>(&Qp[(size_t)(q0 + lr) * 128 + c * 32 + lg * 8]);

  const int ks_row = (tid >> 4);
  const int ks_cb0 = (tid & 15) * 16;
  const int vs_row = (tid >> 3);
  const int vs_cb0 = (tid & 7) * 16;

#define STAGE(bufi, ktv)                                                        \
  {                                                                             \
    _Pragma("unroll")                                                           \
    for (int i = 0; i < 4; ++i) {                                               \
      int krow = i * 16 + ks_row;                                               \
      int kcb = ks_cb0 ^ ((krow & 7) << 4);                                     \
      gload16(Kp + (size_t)((ktv) + krow) * 128 + (kcb >> 1),                   \
              &Kl[bufi][i * 2048 + wave * 512]);                                \
      int vrow = i * 32 + vs_row;                                               \
      int vcb = vs_cb0 ^ ((vrow & 7) << 4);                                     \
      gload16(Vp + (size_t)vrow * 1024 + (ktv) + (vcb >> 1),                    \
              &Vl[bufi][i * 2048 + wave * 512]);                                \
    }                                                                           \
  }

  f32x4 oacc[8];
#pragma unroll
  for (int dt = 0; dt < 8; ++dt) oacc[dt] = (f32x4){0.f, 0.f, 0.f, 0.f};
  float mrun = -3.0e38f;
  float lrun = 0.f;

  STAGE(0, 0);
  __syncthreads();

  int cur = 0;
  for (int t = 0; t < 16; ++t) {
    const int kt = t * 64;
    if (t < 15) STAGE(cur ^ 1, kt + 64);

    f32x4 s[4];
    __builtin_amdgcn_s_setprio(1);
#pragma unroll
    for (int n = 0; n < 4; ++n) {
      f32x4 a = (f32x4){0.f, 0.f, 0.f, 0.f};
      const int krow = n * 16 + lr;
      const int rsw = (krow & 7) << 4;
#pragma unroll
      for (int c = 0; c < 4; ++c) {
        bf16x8 bk = *reinterpret_cast<const bf16x8*>(
            &Kl[cur][krow * 128 + (((c * 64 + lg * 16) ^ rsw) >> 1)]);
        a = MFMA16(bk, aq[c], a);
      }
      s[n] = a;
    }
    __builtin_amdgcn_s_setprio(0);

#pragma unroll
    for (int n = 0; n < 4; ++n) {
      f32x4 pv = *reinterpret_cast<const f32x4*>(&pen[kt + n * 16 + lg * 4]);
#pragma unroll
      for (int i = 0; i < 4; ++i) s[n][i] = s[n][i] * SC2 + pv[i];
    }

    float mn[4];
#pragma unroll
    for (int n = 0; n < 4; ++n)
      mn[n] = fmaxf(fmaxf(s[n][0], s[n][1]), fmaxf(s[n][2], s[n][3]));
    float mx = fmaxf(fmaxf(mn[0], mn[1]), fmaxf(mn[2], mn[3]));
    mx = fmaxf(mx, __shfl_xor(mx, 16));
    mx = fmaxf(mx, __shfl_xor(mx, 32));

    if (!__all(mx <= mrun + 8.0f)) {
      float mnew = fmaxf(mrun, mx);
      float scq = __builtin_amdgcn_exp2f(mrun - mnew);
      mrun = mnew;
      lrun *= scq;
#pragma unroll
      for (int i = 0; i < 4; ++i) {
        float sco = __shfl(scq, lg * 4 + i);
#pragma unroll
        for (int dt = 0; dt < 8; ++dt) oacc[dt][i] *= sco;
      }
    }

    float p[4][4], lsn[4];
#pragma unroll
    for (int n = 0; n < 4; ++n) {
#pragma unroll
      for (int i = 0; i < 4; ++i)
        p[n][i] = __builtin_amdgcn_exp2f(s[n][i] - mrun);
      lsn[n] = (p[n][0] + p[n][1]) + (p[n][2] + p[n][3]);
    }
    float ls = (lsn[0] + lsn[1]) + (lsn[2] + lsn[3]);
    ls += __shfl_xor(ls, 16);
    ls += __shfl_xor(ls, 32);
    lrun += ls;

#pragma unroll
    for (int n = 0; n < 4; ++n)
#pragma unroll
      for (int t2 = 0; t2 < 2; ++t2) {
        unsigned int u;
        asm("v_cvt_pk_bf16_f32 %0, %1, %2"
            : "=v"(u) : "v"(p[n][2 * t2]), "v"(p[n][2 * t2 + 1]));
        *reinterpret_cast<unsigned int*>(
            &myP[lr * 72 + n * 16 + lg * 4 + t2 * 2]) = u;
      }
    bf16x8 pa0 = *reinterpret_cast<const bf16x8*>(&myP[lr * 72 + lg * 8]);
    bf16x8 pa1 = *reinterpret_cast<const bf16x8*>(&myP[lr * 72 + 32 + lg * 8]);

    __builtin_amdgcn_s_setprio(1);
#pragma unroll
    for (int dt = 0; dt < 8; ++dt) {
      const int vrow = dt * 16 + lr;
      const int rsw = (vrow & 7) << 4;
      bf16x8 bv0 = *reinterpret_cast<const bf16x8*>(
          &Vl[cur][vrow * 64 + (((lg * 16) ^ rsw) >> 1)]);
      bf16x8 bv1 = *reinterpret_cast<const bf16x8*>(
          &Vl[cur][vrow * 64 + (((64 + lg * 16) ^ rsw) >> 1)]);
      oacc[dt] = MFMA16(pa0, bv0, oacc[dt]);
      oacc[dt] = MFMA16(pa1, bv1, oacc[dt]);
    }
    __builtin_amdgcn_s_setprio(0);

    __syncthreads();
    cur ^= 1;
  }

  float linv[4];
#pragma unroll
  for (int i = 0; i < 4; ++i) {
    float lq = __shfl(lrun, lg * 4 + i);
    linv[i] = 1.0f / lq;
  }
#pragma unroll
  for (int dt = 0; dt < 8; ++dt)
#pragma unroll
    for (int i = 0; i < 4; ++i)
      Op[(size_t)(q0 + lg * 4 + i) * 128 + dt * 16 + lr] = f2bf(oacc[dt][i] * linv[i]);
}

// ============ Fallback kernels (round-2, 192 MiB workspace) ============
__global__ __launch_bounds__(256) void qkv_proj_old(
    const float* __restrict__ x,
    const float* __restrict__ wq, const float* __restrict__ wk, const float* __restrict__ wv,
    const float* __restrict__ bq, const float* __restrict__ bk, const float* __restrict__ bv,
    unsigned short* __restrict__ Q, unsigned short* __restrict__ K, unsigned short* __restrict__ Vt)
{
  const int tid = threadIdx.x;
  const int wave = tid >> 6, lane = tid & 63;
  const int lr = lane & 15, lg = lane >> 4;
  const int wr = wave >> 1, wc = wave & 1;
  const int mt = blockIdx.x & 7, nt = blockIdx.x >> 3;
  const int b = blockIdx.y, z = blockIdx.z;
  const int l0 = mt * 128, i0 = nt * 128;
  const float* w    = (z == 0) ? wq : (z == 1) ? wk : wv;
  const float* bias = (z == 0) ? bq : (z == 1) ? bk : bv;
  unsigned short* outp = (z == 0) ? Q : (z == 1) ? K : Vt;

  __shared__ __align__(16) unsigned short lA[128 * 40];
  __shared__ __align__(16) unsigned short lB[128 * 40];

  f32x4 acc[4][4];
#pragma unroll
  for (int m = 0; m < 4; ++m)
#pragma unroll
    for (int n = 0; n < 4; ++n) acc[m][n] = (f32x4){0.f, 0.f, 0.f, 0.f};

  const int ad = tid >> 3, aj = tid & 7;
  const int br = tid >> 1, bh2 = tid & 1;

  for (int k0 = 0; k0 < 1024; k0 += 32) {
    const float* xp = x + ((size_t)b * 1024 + k0 + ad) * 1024 + l0;
#pragma unroll
    for (int rep = 0; rep < 4; ++rep) {
      float4 v = *reinterpret_cast<const float4*>(xp + aj * 4 + rep * 32);
      int lb = aj * 4 + rep * 32;
      lA[(lb + 0) * 40 + ad] = f2bf(v.x);
      lA[(lb + 1) * 40 + ad] = f2bf(v.y);
      lA[(lb + 2) * 40 + ad] = f2bf(v.z);
      lA[(lb + 3) * 40 + ad] = f2bf(v.w);
    }
    const float* wp = w + (size_t)(i0 + br) * 1024 + k0 + bh2 * 16;
#pragma unroll
    for (int rep = 0; rep < 4; ++rep) {
      float4 v = *reinterpret_cast<const float4*>(wp + rep * 4);
      int cb = br * 40 + bh2 * 16 + rep * 4;
      lB[cb + 0] = f2bf(v.x); lB[cb + 1] = f2bf(v.y);
      lB[cb + 2] = f2bf(v.z); lB[cb + 3] = f2bf(v.w);
    }
    __syncthreads();
    bf16x8 af[4], bfr[4];
#pragma unroll
    for (int m = 0; m < 4; ++m)
      af[m] = *reinterpret_cast<const bf16x8*>(&lA[(wr * 64 + m * 16 + lr) * 40 + lg * 8]);
#pragma unroll
    for (int n = 0; n < 4; ++n)
      bfr[n] = *reinterpret_cast<const bf16x8*>(&lB[(wc * 64 + n * 16 + lr) * 40 + lg * 8]);
#pragma unroll
    for (int m = 0; m < 4; ++m)
#pragma unroll
      for (int n = 0; n < 4; ++n)
        acc[m][n] = MFMA16(af[m], bfr[n], acc[m][n]);
    __syncthreads();
  }
#pragma unroll
  for (int n = 0; n < 4; ++n) {
    int col = i0 + wc * 64 + n * 16 + lr;
    float bs = bias[col];
    int h = col >> 7, d = col & 127;
#pragma unroll
    for (int m = 0; m < 4; ++m) {
#pragma unroll
      for (int ii = 0; ii < 4; ++ii) {
        int row = l0 + wr * 64 + m * 16 + lg * 4 + ii;
        unsigned short val = f2bf(acc[m][n][ii] + bs);
        if (z < 2)
          outp[(((size_t)b * 8 + h) * 1024 + row) * 128 + d] = val;
        else
          outp[(((size_t)b * 8 + h) * 128 + d) * 1024 + row] = val;
      }
    }
  }
}

__global__ __launch_bounds__(256) void out_proj_old(
    const unsigned short* __restrict__ Obuf, const float* __restrict__ wo,
    const float* __restrict__ bo, float* __restrict__ out)
{
  const int tid = threadIdx.x, wave = tid >> 6, lane = tid & 63;
  const int lr = lane & 15, lg = lane >> 4;
  const int wr = wave >> 1, wc = wave & 1;
  const int mt = blockIdx.x & 7, nt = blockIdx.x >> 3;
  const int b = blockIdx.y;
  const int d0 = mt * 128, l0 = nt * 128;

  __shared__ __align__(16) unsigned short lA[128 * 40];
  __shared__ __align__(16) unsigned short lB[128 * 40];

  f32x4 acc[4][4];
#pragma unroll
  for (int m = 0; m < 4; ++m)
#pragma unroll
    for (int n = 0; n < 4; ++n) acc[m][n] = (f32x4){0.f, 0.f, 0.f, 0.f};

  const int ar = tid >> 1, ah = tid & 1;

  for (int k0 = 0; k0 < 1024; k0 += 32) {
    const float* wp = wo + (size_t)(d0 + ar) * 1024 + k0 + ah * 16;
#pragma unroll
    for (int rep = 0; rep < 4; ++rep) {
      float4 v = *reinterpret_cast<const float4*>(wp + rep * 4);
      int cb = ar * 40 + ah * 16 + rep * 4;
      lA[cb + 0] = f2bf(v.x); lA[cb + 1] = f2bf(v.y);
      lA[cb + 2] = f2bf(v.z); lA[cb + 3] = f2bf(v.w);
    }
    {
      int head = k0 >> 7, dk = (k0 & 127) + ah * 16;
      const unsigned short* op =
          Obuf + (((size_t)b * 8 + head) * 1024 + l0 + ar) * 128 + dk;
#pragma unroll
      for (int rep = 0; rep < 2; ++rep) {
        bf16x8 v = *reinterpret_cast<const bf16x8*>(op + rep * 8);
        *reinterpret_cast<bf16x8*>(&lB[ar * 40 + ah * 16 + rep * 8]) = v;
      }
    }
    __syncthreads();
    bf16x8 af[4], bfr[4];
#pragma unroll
    for (int m = 0; m < 4; ++m)
      af[m] = *reinterpret_cast<const bf16x8*>(&lA[(wr * 64 + m * 16 + lr) * 40 + lg * 8]);
#pragma unroll
    for (int n = 0; n < 4; ++n)
      bfr[n] = *reinterpret_cast<const bf16x8*>(&lB[(wc * 64 + n * 16 + lr) * 40 + lg * 8]);
#pragma unroll
    for (int m = 0; m < 4; ++m)
#pragma unroll
      for (int n = 0; n < 4; ++n)
        acc[m][n] = MFMA16(af[m], bfr[n], acc[m][n]);
    __syncthreads();
  }
#pragma unroll
  for (int m = 0; m < 4; ++m) {
#pragma unroll
    for (int ii = 0; ii < 4; ++ii) {
      int dr = d0 + wr * 64 + m * 16 + lg * 4 + ii;
      float bs = bo[dr];
      float* orow = out + ((size_t)b * 1024 + dr) * 1024 + l0 + wc * 64 + lr;
#pragma unroll
      for (int n = 0; n < 4; ++n)
        orow[n * 16] = acc[m][n][ii] + bs;
    }
  }
}

extern "C" void kernel_launch(void* const* d_in, const int* in_sizes, int n_in,
                              void* d_out, int out_size, void* d_ws, size_t ws_size,
                              hipStream_t stream) {
  const float* x  = (const float*)d_in[0];
  const int* mask = (const int*)d_in[1];
  const float* wq = (const float*)d_in[2];
  const float* bq = (const float*)d_in[3];
  const float* wk = (const float*)d_in[4];
  const float* bk = (const float*)d_in[5];
  const float* wv = (const float*)d_in[6];
  const float* bv = (const float*)d_in[7];
  const float* wo = (const float*)d_in[8];
  const float* bo = (const float*)d_in[9];
  float* out = (float*)d_out;

  const size_t MB64 = (size_t)64 << 20;
  const size_t NEED = (size_t)264 << 20;

  if (ws_size >= NEED) {
    unsigned short* xT   = (unsigned short*)d_ws;
    unsigned short* Q    = (unsigned short*)((char*)d_ws + MB64);
    unsigned short* K    = (unsigned short*)((char*)d_ws + 2 * MB64);
    unsigned short* Vt   = (unsigned short*)((char*)d_ws + 3 * MB64);
    unsigned short* Wqkv = (unsigned short*)((char*)d_ws + 4 * MB64);
    unsigned short* Wo   = Wqkv + (size_t)3 * 1048576;

    x_transpose<<<dim3(16, 16, 32), 256, 0, stream>>>(x, xT);
    w_convert<<<dim3(1024, 4), 256, 0, stream>>>(wq, wk, wv, wo, Wqkv, Wo);
    qkv_gemm8<<<dim3(1536), 512, 0, stream>>>(xT, Wqkv, bq, bk, bv, Q, K, Vt);
    flash_attn<<<dim3(16, 8, 32), 256, 0, stream>>>(Q, K, Vt, mask, Q);
    out_gemm<<<dim3(64, 32), 256, 0, stream>>>(Wo, Q, bo, out);
  } else {
    unsigned short* Q  = (unsigned short*)d_ws;
    unsigned short* K  = Q + (size_t)33554432;
    unsigned short* Vt = K + (size_t)33554432;
    qkv_proj_old<<<dim3(64, 32, 3), 256, 0, stream>>>(x, wq, wk, wv, bq, bk, bv, Q, K, Vt);
    flash_attn<<<dim3(16, 8, 32), 256, 0, stream>>>(Q, K, Vt, mask, Q);
    out_proj_old<<<dim3(64, 32), 256, 0, stream>>>(Q, wo, bo, out);
  }
}

// Round 6
// 652.402 us; speedup vs baseline: 2.6982x; 1.0125x over previous
//
#include <hip/hip_runtime.h>
#include <hip/hip_bf16.h>

typedef __bf16 bf16_t;
typedef bf16_t bf16x8 __attribute__((ext_vector_type(8)));
typedef float f32x4 __attribute__((ext_vector_type(4)));

#define MFMA16(a, b, c) __builtin_amdgcn_mfma_f32_16x16x32_bf16(a, b, c, 0, 0, 0)
#define NEGV -1e30f

__device__ __forceinline__ unsigned short f2bf(float f) {
  union { float f; unsigned int u; } v; v.f = f;
  unsigned int r = v.u + 0x7FFFu + ((v.u >> 16) & 1u);
  return (unsigned short)(r >> 16);
}

__device__ __forceinline__ void gload16(const unsigned short* g, unsigned short* l) {
  __builtin_amdgcn_global_load_lds(
      (const __attribute__((address_space(1))) void*)g,
      (__attribute__((address_space(3))) void*)l, 16, 0, 0);
}

// ============ Kernel P1: x [B,D,L] fp32 -> xT [B,L,D] bf16 ============
__global__ __launch_bounds__(256) void x_transpose(
    const float* __restrict__ x, unsigned short* __restrict__ xT)
{
  const int b = blockIdx.z;
  const int l0 = blockIdx.x * 64, d0 = blockIdx.y * 64;
  __shared__ __align__(16) unsigned short T[64][68];
  const int tid = threadIdx.x;
  const int dl = tid >> 4, lc = (tid & 15) * 4;
#pragma unroll
  for (int rep = 0; rep < 4; ++rep) {
    int d = dl + rep * 16;
    float4 v = *reinterpret_cast<const float4*>(
        x + ((size_t)b * 1024 + d0 + d) * 1024 + l0 + lc);
    ushort4 u;
    u.x = f2bf(v.x); u.y = f2bf(v.y); u.z = f2bf(v.z); u.w = f2bf(v.w);
    *reinterpret_cast<ushort4*>(&T[d][lc]) = u;
  }
  __syncthreads();
  const int dbase = (tid & 15) * 4, lbase = (tid >> 4) * 4;
  ushort4 r0 = *reinterpret_cast<const ushort4*>(&T[dbase + 0][lbase]);
  ushort4 r1 = *reinterpret_cast<const ushort4*>(&T[dbase + 1][lbase]);
  ushort4 r2 = *reinterpret_cast<const ushort4*>(&T[dbase + 2][lbase]);
  ushort4 r3 = *reinterpret_cast<const ushort4*>(&T[dbase + 3][lbase]);
  ushort4 w0 = {r0.x, r1.x, r2.x, r3.x};
  ushort4 w1 = {r0.y, r1.y, r2.y, r3.y};
  ushort4 w2 = {r0.z, r1.z, r2.z, r3.z};
  ushort4 w3 = {r0.w, r1.w, r2.w, r3.w};
  unsigned short* op = xT + ((size_t)b * 1024 + l0 + lbase) * 1024 + d0 + dbase;
  *reinterpret_cast<ushort4*>(op) = w0;
  *reinterpret_cast<ushort4*>(op + 1024) = w1;
  *reinterpret_cast<ushort4*>(op + 2048) = w2;
  *reinterpret_cast<ushort4*>(op + 3072) = w3;
}

// ============ Kernel P2: weights fp32 -> bf16 (Wqkv concat + Wo) ============
__global__ __launch_bounds__(256) void w_convert(
    const float* __restrict__ wq, const float* __restrict__ wk,
    const float* __restrict__ wv, const float* __restrict__ wo,
    unsigned short* __restrict__ Wqkv, unsigned short* __restrict__ Wo)
{
  const int z = blockIdx.y;
  const float* src = (z == 0) ? wq : (z == 1) ? wk : (z == 2) ? wv : wo;
  unsigned short* dst = (z < 3) ? Wqkv + (size_t)z * 1048576 : Wo;
  size_t off = ((size_t)blockIdx.x * 256 + threadIdx.x) * 4;
  float4 v = *reinterpret_cast<const float4*>(src + off);
  ushort4 u = {f2bf(v.x), f2bf(v.y), f2bf(v.z), f2bf(v.w)};
  *reinterpret_cast<ushort4*>(dst + off) = u;
}

// ============ Kernel A: fused QKV GEMM — 256^2 / BK64, 8-phase counted-vmcnt ==
__global__ __launch_bounds__(512, 2) void qkv_gemm8(
    const unsigned short* __restrict__ xT, const unsigned short* __restrict__ Wqkv,
    const float* __restrict__ bq, const float* __restrict__ bk, const float* __restrict__ bv,
    unsigned short* __restrict__ Q, unsigned short* __restrict__ K,
    unsigned short* __restrict__ Vt)
{
  __shared__ __align__(16) unsigned short lds[2][4][8192];  // 128 KiB

  const int tid = threadIdx.x;
  const int wave = tid >> 6, lane = tid & 63;
  const int lr = lane & 15, lg = lane >> 4;
  const int wr = wave >> 2, wc = wave & 3;

  const int bid = blockIdx.x;
  const int swz = (bid & 7) * 192 + (bid >> 3);  // 1536 % 8 == 0: bijective
  const int mt = swz / 12, nt = swz % 12;
  const int m0 = mt * 256, n0 = nt * 256;

  const unsigned short* Ag = xT + (size_t)m0 * 1024;
  const unsigned short* Bg = Wqkv + (size_t)n0 * 1024;

  const int srow = tid >> 2;
  const int schk = (tid & 3) * 8;

#define STAGE_HT(BUF, REG, TI)                                                 \
  {                                                                            \
    const int kt_ = ((TI) < 16 ? (TI) : 15) * 64 + (((REG)&1) * 32) + schk;    \
    const unsigned short* gp_ = (((REG) < 2) ? Ag : Bg);                       \
    _Pragma("unroll")                                                          \
    for (int j_ = 0; j_ < 2; ++j_)                                             \
      gload16(gp_ + (size_t)(j_ * 128 + srow) * 1024 + kt_,                    \
              &lds[BUF][REG][j_ * 4096 + tid * 8]);                            \
  }

#define LDA(BUF, KK, MH, AR)                                                   \
  _Pragma("unroll")                                                            \
  for (int mi_ = 0; mi_ < 4; ++mi_)                                            \
    AR[mi_] = *reinterpret_cast<const bf16x8*>(                                \
        &lds[BUF][KK][(wr * 128 + (MH)*64 + mi_ * 16 + lr) * 32 + lg * 8]);

#define LDB(BUF, KK, BR)                                                       \
  _Pragma("unroll")                                                            \
  for (int n_ = 0; n_ < 4; ++n_)                                               \
    BR[n_] = *reinterpret_cast<const bf16x8*>(                                 \
        &lds[BUF][2 + (KK)][(wc * 64 + n_ * 16 + lr) * 32 + lg * 8]);

#define MM(AR, BR, MH)                                                         \
  __builtin_amdgcn_s_setprio(1);                                               \
  _Pragma("unroll")                                                            \
  for (int mi_ = 0; mi_ < 4; ++mi_)                                            \
    _Pragma("unroll")                                                          \
    for (int n_ = 0; n_ < 4; ++n_)                                             \
      acc[(MH)*4 + mi_][n_] = MFMA16(AR[mi_], BR[n_], acc[(MH)*4 + mi_][n_]);  \
  __builtin_amdgcn_s_setprio(0);

#define BAR()                                                                  \
  {                                                                            \
    asm volatile("" ::: "memory");                                             \
    __builtin_amdgcn_s_barrier();                                              \
    asm volatile("" ::: "memory");                                             \
  }
#define VMW() asm volatile("s_waitcnt vmcnt(10)" ::: "memory")

  f32x4 acc[8][4];
#pragma unroll
  for (int m = 0; m < 8; ++m)
#pragma unroll
    for (int n = 0; n < 4; ++n) acc[m][n] = (f32x4){0.f, 0.f, 0.f, 0.f};

  STAGE_HT(0, 2, 0); STAGE_HT(0, 0, 0); STAGE_HT(0, 3, 0); STAGE_HT(0, 1, 0);
  STAGE_HT(1, 2, 1); STAGE_HT(1, 0, 1); STAGE_HT(1, 3, 1);
  VMW();
  BAR();

  for (int it = 0; it < 8; ++it) {
    const int T = 2 * it;
    bf16x8 a0[4], a1[4], b0[4], b1[4];
    LDB(0, 0, b0); LDA(0, 0, 0, a0);
    STAGE_HT(1, 1, T + 1);
    BAR();
    MM(a0, b0, 0);
    BAR();
    LDA(0, 0, 1, a1);
    STAGE_HT(0, 2, T + 2);
    BAR();
    MM(a1, b0, 1);
    VMW(); BAR();
    LDB(0, 1, b1); LDA(0, 1, 0, a0);
    STAGE_HT(0, 0, T + 2);
    BAR();
    MM(a0, b1, 0);
    BAR();
    LDA(0, 1, 1, a1);
    STAGE_HT(0, 3, T + 2);
    BAR();
    MM(a1, b1, 1);
    VMW(); BAR();
    LDB(1, 0, b0); LDA(1, 0, 0, a0);
    STAGE_HT(0, 1, T + 2);
    BAR();
    MM(a0, b0, 0);
    BAR();
    LDA(1, 0, 1, a1);
    STAGE_HT(1, 2, T + 3);
    BAR();
    MM(a1, b0, 1);
    VMW(); BAR();
    LDB(1, 1, b1); LDA(1, 1, 0, a0);
    STAGE_HT(1, 0, T + 3);
    BAR();
    MM(a0, b1, 0);
    BAR();
    LDA(1, 1, 1, a1);
    STAGE_HT(1, 3, T + 3);
    BAR();
    MM(a1, b1, 1);
    VMW(); BAR();
  }

  const int zi = n0 >> 10;
  const float* bias = (zi == 0) ? bq : (zi == 1) ? bk : bv;
  const int b = m0 >> 10;
  const int lbase = (m0 & 1023) + wr * 128;

  if (zi < 2) {
    unsigned short* op = ((zi == 0) ? Q : K);
#pragma unroll
    for (int n = 0; n < 4; ++n) {
      const int col = (n0 & 1023) + wc * 64 + n * 16 + lr;
      const int h = col >> 7, d = col & 127;
      const float bs = bias[col];
      unsigned short* hp = op + ((size_t)b * 8 + h) * 131072 + d;
#pragma unroll
      for (int m = 0; m < 8; ++m)
#pragma unroll
        for (int ii = 0; ii < 4; ++ii) {
          int l = lbase + m * 16 + lg * 4 + ii;
          hp[(size_t)l * 128] = f2bf(acc[m][n][ii] + bs);
        }
    }
  } else {
#pragma unroll
    for (int n = 0; n < 4; ++n) {
      const int col = (n0 & 1023) + wc * 64 + n * 16 + lr;
      const int h = col >> 7, d = col & 127;
      const float bs = bias[col];
      unsigned short* hp = Vt + ((size_t)b * 8 + h) * 131072 + (size_t)d * 1024;
#pragma unroll
      for (int m = 0; m < 8; ++m) {
        int l = lbase + m * 16 + lg * 4;
        ushort4 u = {f2bf(acc[m][n][0] + bs), f2bf(acc[m][n][1] + bs),
                     f2bf(acc[m][n][2] + bs), f2bf(acc[m][n][3] + bs)};
        *reinterpret_cast<ushort4*>(&hp[l]) = u;
      }
    }
  }
#undef STAGE_HT
}

// ============ Kernel C: out projection — 256^2 / BK64, 8-phase ============
// out[b,d,l] = Wo[d,:] . O'[l,:] + bo[d]; O' rows at O[((b*8+h)*1024+l)*128+dk]
__global__ __launch_bounds__(512, 2) void out_gemm8(
    const unsigned short* __restrict__ Wo, const unsigned short* __restrict__ O,
    const float* __restrict__ bo, float* __restrict__ out)
{
  __shared__ __align__(16) unsigned short lds[2][4][8192];

  const int tid = threadIdx.x;
  const int wave = tid >> 6, lane = tid & 63;
  const int lr = lane & 15, lg = lane >> 4;
  const int wr = wave >> 2, wc = wave & 3;

  const int b = blockIdx.y;
  const int bid = blockIdx.x;                  // 16 tiles per batch
  const int swz = (bid & 7) * 2 + (bid >> 3);  // bijective (16 % 8 == 0)
  const int mt = swz >> 2, nt = swz & 3;
  const int d0 = mt * 256, l0 = nt * 256;

  const unsigned short* Ag = Wo + (size_t)d0 * 1024;
  const unsigned short* Og = O + (size_t)b * 8 * 131072;

  const int srow = tid >> 2;
  const int schk = (tid & 3) * 8;

#define STAGE_HT(BUF, REG, TI)                                                 \
  {                                                                            \
    const int kt_ = ((TI) < 16 ? (TI) : 15) * 64 + (((REG)&1) * 32) + schk;    \
    if ((REG) < 2) {                                                           \
      _Pragma("unroll")                                                        \
      for (int j_ = 0; j_ < 2; ++j_)                                           \
        gload16(Ag + (size_t)(j_ * 128 + srow) * 1024 + kt_,                   \
                &lds[BUF][REG][j_ * 4096 + tid * 8]);                          \
    } else {                                                                   \
      const int h_ = kt_ >> 7, dk_ = kt_ & 127;                                \
      _Pragma("unroll")                                                        \
      for (int j_ = 0; j_ < 2; ++j_)                                           \
        gload16(Og + (size_t)h_ * 131072 +                                     \
                    (size_t)(l0 + j_ * 128 + srow) * 128 + dk_,                \
                &lds[BUF][REG][j_ * 4096 + tid * 8]);                          \
    }                                                                          \
  }

  f32x4 acc[8][4];
#pragma unroll
  for (int m = 0; m < 8; ++m)
#pragma unroll
    for (int n = 0; n < 4; ++n) acc[m][n] = (f32x4){0.f, 0.f, 0.f, 0.f};

  STAGE_HT(0, 2, 0); STAGE_HT(0, 0, 0); STAGE_HT(0, 3, 0); STAGE_HT(0, 1, 0);
  STAGE_HT(1, 2, 1); STAGE_HT(1, 0, 1); STAGE_HT(1, 3, 1);
  VMW();
  BAR();

  for (int it = 0; it < 8; ++it) {
    const int T = 2 * it;
    bf16x8 a0[4], a1[4], b0[4], b1[4];
    LDB(0, 0, b0); LDA(0, 0, 0, a0);
    STAGE_HT(1, 1, T + 1);
    BAR();
    MM(a0, b0, 0);
    BAR();
    LDA(0, 0, 1, a1);
    STAGE_HT(0, 2, T + 2);
    BAR();
    MM(a1, b0, 1);
    VMW(); BAR();
    LDB(0, 1, b1); LDA(0, 1, 0, a0);
    STAGE_HT(0, 0, T + 2);
    BAR();
    MM(a0, b1, 0);
    BAR();
    LDA(0, 1, 1, a1);
    STAGE_HT(0, 3, T + 2);
    BAR();
    MM(a1, b1, 1);
    VMW(); BAR();
    LDB(1, 0, b0); LDA(1, 0, 0, a0);
    STAGE_HT(0, 1, T + 2);
    BAR();
    MM(a0, b0, 0);
    BAR();
    LDA(1, 0, 1, a1);
    STAGE_HT(1, 2, T + 3);
    BAR();
    MM(a1, b0, 1);
    VMW(); BAR();
    LDB(1, 1, b1); LDA(1, 1, 0, a0);
    STAGE_HT(1, 0, T + 3);
    BAR();
    MM(a0, b1, 0);
    BAR();
    LDA(1, 1, 1, a1);
    STAGE_HT(1, 3, T + 3);
    BAR();
    MM(a1, b1, 1);
    VMW(); BAR();
  }

#pragma unroll
  for (int m = 0; m < 8; ++m) {
#pragma unroll
    for (int ii = 0; ii < 4; ++ii) {
      int dr = d0 + wr * 128 + m * 16 + lg * 4 + ii;
      float bs = bo[dr];
      float* orow = out + ((size_t)b * 1024 + dr) * 1024 + l0 + wc * 64 + lr;
#pragma unroll
      for (int n = 0; n < 4; ++n)
        orow[n * 16] = acc[m][n][ii] + bs;
    }
  }
#undef STAGE_HT
#undef LDA
#undef LDB
#undef MM
#undef BAR
#undef VMW
}

// ============ Kernel B: flash attention, KVBLK=32, 41 KiB LDS (3 blk/CU) =====
__global__ __launch_bounds__(256) void flash_attn(
    const unsigned short* __restrict__ Q, const unsigned short* __restrict__ Kb,
    const unsigned short* __restrict__ Vt, const int* __restrict__ mask,
    unsigned short* __restrict__ O)
{
  const int tid = threadIdx.x, wave = tid >> 6, lane = tid & 63;
  const int lr = lane & 15, lg = lane >> 4;
  const int qt = blockIdx.x, h = blockIdx.y, b = blockIdx.z;
  const size_t bh = (size_t)b * 8 + h;
  const unsigned short* Qp = Q + bh * 131072;
  const unsigned short* Kp = Kb + bh * 131072;
  const unsigned short* Vp = Vt + bh * 131072;
  unsigned short* Op = O + bh * 131072;
  const int q0 = qt * 64 + wave * 16;
  const float SC2 = 0.12751744f;        // (1/sqrt(128)) * log2(e)
  const float NEG2 = -1.442695e30f;     // -1e30 * log2(e)

  __shared__ __align__(16) unsigned short Kl[2][4096];   // [32 kv][128 d], 2x8KB
  __shared__ __align__(16) unsigned short Vl[2][4096];   // [128 d][32 kv], 2x8KB
  __shared__ __align__(16) unsigned short plds[4][16 * 40];
  __shared__ float pen[1024];

  {
    const int4 mv = *reinterpret_cast<const int4*>(mask + b * 1024 + tid * 4);
    float4 pv;
    pv.x = mv.x ? NEG2 : 0.f; pv.y = mv.y ? NEG2 : 0.f;
    pv.z = mv.z ? NEG2 : 0.f; pv.w = mv.w ? NEG2 : 0.f;
    *reinterpret_cast<float4*>(&pen[tid * 4]) = pv;
  }

  unsigned short* myP = plds[wave];

  bf16x8 aq[4];
#pragma unroll
  for (int c = 0; c < 4; ++c)
    aq[c] = *reinterpret_cast<const bf16x8*>(&Qp[(size_t)(q0 + lr) * 128 + c * 32 + lg * 8]);

  // K: [32][128] rows 256B, XOR (row&7)<<4 (involution: row bits >= b8).
  // V: [128][32] rows 64B, XOR ((r^(r>>2))&3)<<4 (involution: row bits >= b6).
#define STAGE(bufi, ktv)                                                        \
  {                                                                             \
    _Pragma("unroll")                                                           \
    for (int i = 0; i < 2; ++i) {                                               \
      int krow = i * 16 + (tid >> 4);                                           \
      int kcb = ((tid & 15) * 16) ^ ((krow & 7) << 4);                          \
      gload16(Kp + (size_t)((ktv) + krow) * 128 + (kcb >> 1),                   \
              &Kl[bufi][i * 2048 + tid * 8]);                                   \
      int aoff = i * 4096 + tid * 16;                                           \
      int r_ = aoff >> 6;                                                       \
      int Lb = aoff ^ (((r_ ^ (r_ >> 2)) & 3) << 4);                            \
      gload16(Vp + (size_t)(Lb >> 6) * 1024 + (ktv) + ((Lb & 63) >> 1),         \
              &Vl[bufi][i * 2048 + tid * 8]);                                   \
    }                                                                           \
  }

  f32x4 oacc[8];
#pragma unroll
  for (int dt = 0; dt < 8; ++dt) oacc[dt] = (f32x4){0.f, 0.f, 0.f, 0.f};
  float mrun = -3.0e38f;
  float lrun = 0.f;

  STAGE(0, 0);
  __syncthreads();

  int cur = 0;
  for (int t = 0; t < 32; ++t) {
    const int kt = t * 32;
    if (t < 31) STAGE(cur ^ 1, kt + 32);

    // ---- S^T = K Q (swapped operands) ----
    f32x4 s[2];
    __builtin_amdgcn_s_setprio(1);
#pragma unroll
    for (int n = 0; n < 2; ++n) {
      f32x4 a = (f32x4){0.f, 0.f, 0.f, 0.f};
      const int krow = n * 16 + lr;
      const int rsw = (krow & 7) << 4;
#pragma unroll
      for (int c = 0; c < 4; ++c) {
        bf16x8 bk = *reinterpret_cast<const bf16x8*>(
            &Kl[cur][krow * 128 + (((c * 64 + lg * 16) ^ rsw) >> 1)]);
        a = MFMA16(bk, aq[c], a);
      }
      s[n] = a;
    }
    __builtin_amdgcn_s_setprio(0);

    // ---- scale + mask (key = kt + n*16 + lg*4 + i) ----
#pragma unroll
    for (int n = 0; n < 2; ++n) {
      f32x4 pv = *reinterpret_cast<const f32x4*>(&pen[kt + n * 16 + lg * 4]);
#pragma unroll
      for (int i = 0; i < 4; ++i) s[n][i] = s[n][i] * SC2 + pv[i];
    }

    // ---- max: 7-op lane tree + 2 shfl ----
    float mx = fmaxf(fmaxf(fmaxf(s[0][0], s[0][1]), fmaxf(s[0][2], s[0][3])),
                     fmaxf(fmaxf(s[1][0], s[1][1]), fmaxf(s[1][2], s[1][3])));
    mx = fmaxf(mx, __shfl_xor(mx, 16));
    mx = fmaxf(mx, __shfl_xor(mx, 32));

    // ---- defer-max (T13) ----
    if (!__all(mx <= mrun + 8.0f)) {
      float mnew = fmaxf(mrun, mx);
      float scq = __builtin_amdgcn_exp2f(mrun - mnew);
      mrun = mnew;
      lrun *= scq;
#pragma unroll
      for (int i = 0; i < 4; ++i) {
        float sco = __shfl(scq, lg * 4 + i);
#pragma unroll
        for (int dt = 0; dt < 8; ++dt) oacc[dt][i] *= sco;
      }
    }

    // ---- p = exp2(s - mrun); sum tree + 2 shfl ----
    float p[2][4];
#pragma unroll
    for (int n = 0; n < 2; ++n)
#pragma unroll
      for (int i = 0; i < 4; ++i)
        p[n][i] = __builtin_amdgcn_exp2f(s[n][i] - mrun);
    float ls = ((p[0][0] + p[0][1]) + (p[0][2] + p[0][3])) +
               ((p[1][0] + p[1][1]) + (p[1][2] + p[1][3]));
    ls += __shfl_xor(ls, 16);
    ls += __shfl_xor(ls, 32);
    lrun += ls;

    // ---- pack P -> LDS row q=lr (4 b32 writes), read 1 A-frag ----
#pragma unroll
    for (int n = 0; n < 2; ++n)
#pragma unroll
      for (int t2 = 0; t2 < 2; ++t2) {
        unsigned int u;
        asm("v_cvt_pk_bf16_f32 %0, %1, %2"
            : "=v"(u) : "v"(p[n][2 * t2]), "v"(p[n][2 * t2 + 1]));
        *reinterpret_cast<unsigned int*>(
            &myP[lr * 40 + n * 16 + lg * 4 + t2 * 2]) = u;
      }
    bf16x8 pa0 = *reinterpret_cast<const bf16x8*>(&myP[lr * 40 + lg * 8]);

    // ---- O += P V ----
    __builtin_amdgcn_s_setprio(1);
#pragma unroll
    for (int dt = 0; dt < 8; ++dt) {
      const int rr = dt * 16 + lr;
      const int aL = rr * 64 + lg * 16;
      const int ph = aL ^ (((rr ^ (rr >> 2)) & 3) << 4);
      bf16x8 bv = *reinterpret_cast<const bf16x8*>(&Vl[cur][ph >> 1]);
      oacc[dt] = MFMA16(pa0, bv, oacc[dt]);
    }
    __builtin_amdgcn_s_setprio(0);

    __syncthreads();
    cur ^= 1;
  }

  float linv[4];
#pragma unroll
  for (int i = 0; i < 4; ++i) {
    float lq = __shfl(lrun, lg * 4 + i);
    linv[i] = 1.0f / lq;
  }
#pragma unroll
  for (int dt = 0; dt < 8; ++dt)
#pragma unroll
    for (int i = 0; i < 4; ++i)
      Op[(size_t)(q0 + lg * 4 + i) * 128 + dt * 16 + lr] = f2bf(oacc[dt][i] * linv[i]);
#undef STAGE
}

// ============ Fallback kernels (round-2, 192 MiB workspace) ============
__global__ __launch_bounds__(256) void qkv_proj_old(
    const float* __restrict__ x,
    const float* __restrict__ wq, const float* __restrict__ wk, const float* __restrict__ wv,
    const float* __restrict__ bq, const float* __restrict__ bk, const float* __restrict__ bv,
    unsigned short* __restrict__ Q, unsigned short* __restrict__ K, unsigned short* __restrict__ Vt)
{
  const int tid = threadIdx.x;
  const int wave = tid >> 6, lane = tid & 63;
  const int lr = lane & 15, lg = lane >> 4;
  const int wr = wave >> 1, wc = wave & 1;
  const int mt = blockIdx.x & 7, nt = blockIdx.x >> 3;
  const int b = blockIdx.y, z = blockIdx.z;
  const int l0 = mt * 128, i0 = nt * 128;
  const float* w    = (z == 0) ? wq : (z == 1) ? wk : wv;
  const float* bias = (z == 0) ? bq : (z == 1) ? bk : bv;
  unsigned short* outp = (z == 0) ? Q : (z == 1) ? K : Vt;

  __shared__ __align__(16) unsigned short lA[128 * 40];
  __shared__ __align__(16) unsigned short lB[128 * 40];

  f32x4 acc[4][4];
#pragma unroll
  for (int m = 0; m < 4; ++m)
#pragma unroll
    for (int n = 0; n < 4; ++n) acc[m][n] = (f32x4){0.f, 0.f, 0.f, 0.f};

  const int ad = tid >> 3, aj = tid & 7;
  const int br = tid >> 1, bh2 = tid & 1;

  for (int k0 = 0; k0 < 1024; k0 += 32) {
    const float* xp = x + ((size_t)b * 1024 + k0 + ad) * 1024 + l0;
#pragma unroll
    for (int rep = 0; rep < 4; ++rep) {
      float4 v = *reinterpret_cast<const float4*>(xp + aj * 4 + rep * 32);
      int lb = aj * 4 + rep * 32;
      lA[(lb + 0) * 40 + ad] = f2bf(v.x);
      lA[(lb + 1) * 40 + ad] = f2bf(v.y);
      lA[(lb + 2) * 40 + ad] = f2bf(v.z);
      lA[(lb + 3) * 40 + ad] = f2bf(v.w);
    }
    const float* wp = w + (size_t)(i0 + br) * 1024 + k0 + bh2 * 16;
#pragma unroll
    for (int rep = 0; rep < 4; ++rep) {
      float4 v = *reinterpret_cast<const float4*>(wp + rep * 4);
      int cb = br * 40 + bh2 * 16 + rep * 4;
      lB[cb + 0] = f2bf(v.x); lB[cb + 1] = f2bf(v.y);
      lB[cb + 2] = f2bf(v.z); lB[cb + 3] = f2bf(v.w);
    }
    __syncthreads();
    bf16x8 af[4], bfr[4];
#pragma unroll
    for (int m = 0; m < 4; ++m)
      af[m] = *reinterpret_cast<const bf16x8*>(&lA[(wr * 64 + m * 16 + lr) * 40 + lg * 8]);
#pragma unroll
    for (int n = 0; n < 4; ++n)
      bfr[n] = *reinterpret_cast<const bf16x8*>(&lB[(wc * 64 + n * 16 + lr) * 40 + lg * 8]);
#pragma unroll
    for (int m = 0; m < 4; ++m)
#pragma unroll
      for (int n = 0; n < 4; ++n)
        acc[m][n] = MFMA16(af[m], bfr[n], acc[m][n]);
    __syncthreads();
  }
#pragma unroll
  for (int n = 0; n < 4; ++n) {
    int col = i0 + wc * 64 + n * 16 + lr;
    float bs = bias[col];
    int h = col >> 7, d = col & 127;
#pragma unroll
    for (int m = 0; m < 4; ++m) {
#pragma unroll
      for (int ii = 0; ii < 4; ++ii) {
        int row = l0 + wr * 64 + m * 16 + lg * 4 + ii;
        unsigned short val = f2bf(acc[m][n][ii] + bs);
        if (z < 2)
          outp[(((size_t)b * 8 + h) * 1024 + row) * 128 + d] = val;
        else
          outp[(((size_t)b * 8 + h) * 128 + d) * 1024 + row] = val;
      }
    }
  }
}

__global__ __launch_bounds__(256) void out_proj_old(
    const unsigned short* __restrict__ Obuf, const float* __restrict__ wo,
    const float* __restrict__ bo, float* __restrict__ out)
{
  const int tid = threadIdx.x, wave = tid >> 6, lane = tid & 63;
  const int lr = lane & 15, lg = lane >> 4;
  const int wr = wave >> 1, wc = wave & 1;
  const int mt = blockIdx.x & 7, nt = blockIdx.x >> 3;
  const int b = blockIdx.y;
  const int d0 = mt * 128, l0 = nt * 128;

  __shared__ __align__(16) unsigned short lA[128 * 40];
  __shared__ __align__(16) unsigned short lB[128 * 40];

  f32x4 acc[4][4];
#pragma unroll
  for (int m = 0; m < 4; ++m)
#pragma unroll
    for (int n = 0; n < 4; ++n) acc[m][n] = (f32x4){0.f, 0.f, 0.f, 0.f};

  const int ar = tid >> 1, ah = tid & 1;

  for (int k0 = 0; k0 < 1024; k0 += 32) {
    const float* wp = wo + (size_t)(d0 + ar) * 1024 + k0 + ah * 16;
#pragma unroll
    for (int rep = 0; rep < 4; ++rep) {
      float4 v = *reinterpret_cast<const float4*>(wp + rep * 4);
      int cb = ar * 40 + ah * 16 + rep * 4;
      lA[cb + 0] = f2bf(v.x); lA[cb + 1] = f2bf(v.y);
      lA[cb + 2] = f2bf(v.z); lA[cb + 3] = f2bf(v.w);
    }
    {
      int head = k0 >> 7, dk = (k0 & 127) + ah * 16;
      const unsigned short* op =
          Obuf + (((size_t)b * 8 + head) * 1024 + l0 + ar) * 128 + dk;
#pragma unroll
      for (int rep = 0; rep < 2; ++rep) {
        bf16x8 v = *reinterpret_cast<const bf16x8*>(op + rep * 8);
        *reinterpret_cast<bf16x8*>(&lB[ar * 40 + ah * 16 + rep * 8]) = v;
      }
    }
    __syncthreads();
    bf16x8 af[4], bfr[4];
#pragma unroll
    for (int m = 0; m < 4; ++m)
      af[m] = *reinterpret_cast<const bf16x8*>(&lA[(wr * 64 + m * 16 + lr) * 40 + lg * 8]);
#pragma unroll
    for (int n = 0; n < 4; ++n)
      bfr[n] = *reinterpret_cast<const bf16x8*>(&lB[(wc * 64 + n * 16 + lr) * 40 + lg * 8]);
#pragma unroll
    for (int m = 0; m < 4; ++m)
#pragma unroll
      for (int n = 0; n < 4; ++n)
        acc[m][n] = MFMA16(af[m], bfr[n], acc[m][n]);
    __syncthreads();
  }
#pragma unroll
  for (int m = 0; m < 4; ++m) {
#pragma unroll
    for (int ii = 0; ii < 4; ++ii) {
      int dr = d0 + wr * 64 + m * 16 + lg * 4 + ii;
      float bs = bo[dr];
      float* orow = out + ((size_t)b * 1024 + dr) * 1024 + l0 + wc * 64 + lr;
#pragma unroll
      for (int n = 0; n < 4; ++n)
        orow[n * 16] = acc[m][n][ii] + bs;
    }
  }
}

extern "C" void kernel_launch(void* const* d_in, const int* in_sizes, int n_in,
                              void* d_out, int out_size, void* d_ws, size_t ws_size,
                              hipStream_t stream) {
  const float* x  = (const float*)d_in[0];
  const int* mask = (const int*)d_in[1];
  const float* wq = (const float*)d_in[2];
  const float* bq = (const float*)d_in[3];
  const float* wk = (const float*)d_in[4];
  const float* bk = (const float*)d_in[5];
  const float* wv = (const float*)d_in[6];
  const float* bv = (const float*)d_in[7];
  const float* wo = (const float*)d_in[8];
  const float* bo = (const float*)d_in[9];
  float* out = (float*)d_out;

  const size_t MB64 = (size_t)64 << 20;
  const size_t NEED = (size_t)264 << 20;

  if (ws_size >= NEED) {
    unsigned short* xT   = (unsigned short*)d_ws;
    unsigned short* Q    = (unsigned short*)((char*)d_ws + MB64);
    unsigned short* K    = (unsigned short*)((char*)d_ws + 2 * MB64);
    unsigned short* Vt   = (unsigned short*)((char*)d_ws + 3 * MB64);
    unsigned short* Wqkv = (unsigned short*)((char*)d_ws + 4 * MB64);
    unsigned short* Wo   = Wqkv + (size_t)3 * 1048576;

    x_transpose<<<dim3(16, 16, 32), 256, 0, stream>>>(x, xT);
    w_convert<<<dim3(1024, 4), 256, 0, stream>>>(wq, wk, wv, wo, Wqkv, Wo);
    qkv_gemm8<<<dim3(1536), 512, 0, stream>>>(xT, Wqkv, bq, bk, bv, Q, K, Vt);
    flash_attn<<<dim3(16, 8, 32), 256, 0, stream>>>(Q, K, Vt, mask, Q);
    out_gemm8<<<dim3(16, 32), 512, 0, stream>>>(Wo, Q, bo, out);
  } else {
    unsigned short* Q  = (unsigned short*)d_ws;
    unsigned short* K  = Q + (size_t)33554432;
    unsigned short* Vt = K + (size_t)33554432;
    qkv_proj_old<<<dim3(64, 32, 3), 256, 0, stream>>>(x, wq, wk, wv, bq, bk, bv, Q, K, Vt);
    flash_attn<<<dim3(16, 8, 32), 256, 0, stream>>>(Q, K, Vt, mask, Q);
    out_proj_old<<<dim3(64, 32), 256, 0, stream>>>(Q, wo, bo, out);
  }
}

// Round 7
// 600.855 us; speedup vs baseline: 2.9297x; 1.0858x over previous
//
#include <hip/hip_runtime.h>
#include <hip/hip_bf16.h>

typedef __bf16 bf16_t;
typedef bf16_t bf16x8 __attribute__((ext_vector_type(8)));
typedef float f32x4 __attribute__((ext_vector_type(4)));

#define MFMA16(a, b, c) __builtin_amdgcn_mfma_f32_16x16x32_bf16(a, b, c, 0, 0, 0)
#define NEGV -1e30f

__device__ __forceinline__ unsigned short f2bf(float f) {
  union { float f; unsigned int u; } v; v.f = f;
  unsigned int r = v.u + 0x7FFFu + ((v.u >> 16) & 1u);
  return (unsigned short)(r >> 16);
}

__device__ __forceinline__ void gload16(const unsigned short* g, unsigned short* l) {
  __builtin_amdgcn_global_load_lds(
      (const __attribute__((address_space(1))) void*)g,
      (__attribute__((address_space(3))) void*)l, 16, 0, 0);
}

// ============ Kernel P1: x [B,D,L] fp32 -> xT [B,L,D] bf16 ============
__global__ __launch_bounds__(256) void x_transpose(
    const float* __restrict__ x, unsigned short* __restrict__ xT)
{
  const int b = blockIdx.z;
  const int l0 = blockIdx.x * 64, d0 = blockIdx.y * 64;
  __shared__ __align__(16) unsigned short T[64][68];
  const int tid = threadIdx.x;
  const int dl = tid >> 4, lc = (tid & 15) * 4;
#pragma unroll
  for (int rep = 0; rep < 4; ++rep) {
    int d = dl + rep * 16;
    float4 v = *reinterpret_cast<const float4*>(
        x + ((size_t)b * 1024 + d0 + d) * 1024 + l0 + lc);
    ushort4 u;
    u.x = f2bf(v.x); u.y = f2bf(v.y); u.z = f2bf(v.z); u.w = f2bf(v.w);
    *reinterpret_cast<ushort4*>(&T[d][lc]) = u;
  }
  __syncthreads();
  const int dbase = (tid & 15) * 4, lbase = (tid >> 4) * 4;
  ushort4 r0 = *reinterpret_cast<const ushort4*>(&T[dbase + 0][lbase]);
  ushort4 r1 = *reinterpret_cast<const ushort4*>(&T[dbase + 1][lbase]);
  ushort4 r2 = *reinterpret_cast<const ushort4*>(&T[dbase + 2][lbase]);
  ushort4 r3 = *reinterpret_cast<const ushort4*>(&T[dbase + 3][lbase]);
  ushort4 w0 = {r0.x, r1.x, r2.x, r3.x};
  ushort4 w1 = {r0.y, r1.y, r2.y, r3.y};
  ushort4 w2 = {r0.z, r1.z, r2.z, r3.z};
  ushort4 w3 = {r0.w, r1.w, r2.w, r3.w};
  unsigned short* op = xT + ((size_t)b * 1024 + l0 + lbase) * 1024 + d0 + dbase;
  *reinterpret_cast<ushort4*>(op) = w0;
  *reinterpret_cast<ushort4*>(op + 1024) = w1;
  *reinterpret_cast<ushort4*>(op + 2048) = w2;
  *reinterpret_cast<ushort4*>(op + 3072) = w3;
}

// ============ Kernel P2: weights fp32 -> bf16 (Wqkv concat + Wo) ============
__global__ __launch_bounds__(256) void w_convert(
    const float* __restrict__ wq, const float* __restrict__ wk,
    const float* __restrict__ wv, const float* __restrict__ wo,
    unsigned short* __restrict__ Wqkv, unsigned short* __restrict__ Wo)
{
  const int z = blockIdx.y;
  const float* src = (z == 0) ? wq : (z == 1) ? wk : (z == 2) ? wv : wo;
  unsigned short* dst = (z < 3) ? Wqkv + (size_t)z * 1048576 : Wo;
  size_t off = ((size_t)blockIdx.x * 256 + threadIdx.x) * 4;
  float4 v = *reinterpret_cast<const float4*>(src + off);
  ushort4 u = {f2bf(v.x), f2bf(v.y), f2bf(v.z), f2bf(v.w)};
  *reinterpret_cast<ushort4*>(dst + off) = u;
}

// ============ Kernel A: fused QKV GEMM — 256^2 / BK64, 8-phase counted-vmcnt ==
__global__ __launch_bounds__(512, 2) void qkv_gemm8(
    const unsigned short* __restrict__ xT, const unsigned short* __restrict__ Wqkv,
    const float* __restrict__ bq, const float* __restrict__ bk, const float* __restrict__ bv,
    unsigned short* __restrict__ Q, unsigned short* __restrict__ K,
    unsigned short* __restrict__ Vt)
{
  __shared__ __align__(16) unsigned short lds[2][4][8192];  // 128 KiB

  const int tid = threadIdx.x;
  const int wave = tid >> 6, lane = tid & 63;
  const int lr = lane & 15, lg = lane >> 4;
  const int wr = wave >> 2, wc = wave & 3;

  const int bid = blockIdx.x;
  const int swz = (bid & 7) * 192 + (bid >> 3);  // 1536 % 8 == 0: bijective
  const int mt = swz / 12, nt = swz % 12;
  const int m0 = mt * 256, n0 = nt * 256;

  const unsigned short* Ag = xT + (size_t)m0 * 1024;
  const unsigned short* Bg = Wqkv + (size_t)n0 * 1024;

  const int srow = tid >> 2;
  const int schk = (tid & 3) * 8;

#define STAGE_HT(BUF, REG, TI)                                                 \
  {                                                                            \
    const int kt_ = ((TI) < 16 ? (TI) : 15) * 64 + (((REG)&1) * 32) + schk;    \
    const unsigned short* gp_ = (((REG) < 2) ? Ag : Bg);                       \
    _Pragma("unroll")                                                          \
    for (int j_ = 0; j_ < 2; ++j_)                                             \
      gload16(gp_ + (size_t)(j_ * 128 + srow) * 1024 + kt_,                    \
              &lds[BUF][REG][j_ * 4096 + tid * 8]);                            \
  }

#define LDA(BUF, KK, MH, AR)                                                   \
  _Pragma("unroll")                                                            \
  for (int mi_ = 0; mi_ < 4; ++mi_)                                            \
    AR[mi_] = *reinterpret_cast<const bf16x8*>(                                \
        &lds[BUF][KK][(wr * 128 + (MH)*64 + mi_ * 16 + lr) * 32 + lg * 8]);

#define LDB(BUF, KK, BR)                                                       \
  _Pragma("unroll")                                                            \
  for (int n_ = 0; n_ < 4; ++n_)                                               \
    BR[n_] = *reinterpret_cast<const bf16x8*>(                                 \
        &lds[BUF][2 + (KK)][(wc * 64 + n_ * 16 + lr) * 32 + lg * 8]);

#define MM(AR, BR, MH)                                                         \
  __builtin_amdgcn_s_setprio(1);                                               \
  _Pragma("unroll")                                                            \
  for (int mi_ = 0; mi_ < 4; ++mi_)                                            \
    _Pragma("unroll")                                                          \
    for (int n_ = 0; n_ < 4; ++n_)                                             \
      acc[(MH)*4 + mi_][n_] = MFMA16(AR[mi_], BR[n_], acc[(MH)*4 + mi_][n_]);  \
  __builtin_amdgcn_s_setprio(0);

#define BAR()                                                                  \
  {                                                                            \
    asm volatile("" ::: "memory");                                             \
    __builtin_amdgcn_s_barrier();                                              \
    asm volatile("" ::: "memory");                                             \
  }
#define VMW() asm volatile("s_waitcnt vmcnt(10)" ::: "memory")

  f32x4 acc[8][4];
#pragma unroll
  for (int m = 0; m < 8; ++m)
#pragma unroll
    for (int n = 0; n < 4; ++n) acc[m][n] = (f32x4){0.f, 0.f, 0.f, 0.f};

  STAGE_HT(0, 2, 0); STAGE_HT(0, 0, 0); STAGE_HT(0, 3, 0); STAGE_HT(0, 1, 0);
  STAGE_HT(1, 2, 1); STAGE_HT(1, 0, 1); STAGE_HT(1, 3, 1);
  VMW();
  BAR();

  for (int it = 0; it < 8; ++it) {
    const int T = 2 * it;
    bf16x8 a0[4], a1[4], b0[4], b1[4];
    LDB(0, 0, b0); LDA(0, 0, 0, a0);
    STAGE_HT(1, 1, T + 1);
    BAR();
    MM(a0, b0, 0);
    BAR();
    LDA(0, 0, 1, a1);
    STAGE_HT(0, 2, T + 2);
    BAR();
    MM(a1, b0, 1);
    VMW(); BAR();
    LDB(0, 1, b1); LDA(0, 1, 0, a0);
    STAGE_HT(0, 0, T + 2);
    BAR();
    MM(a0, b1, 0);
    BAR();
    LDA(0, 1, 1, a1);
    STAGE_HT(0, 3, T + 2);
    BAR();
    MM(a1, b1, 1);
    VMW(); BAR();
    LDB(1, 0, b0); LDA(1, 0, 0, a0);
    STAGE_HT(0, 1, T + 2);
    BAR();
    MM(a0, b0, 0);
    BAR();
    LDA(1, 0, 1, a1);
    STAGE_HT(1, 2, T + 3);
    BAR();
    MM(a1, b0, 1);
    VMW(); BAR();
    LDB(1, 1, b1); LDA(1, 1, 0, a0);
    STAGE_HT(1, 0, T + 3);
    BAR();
    MM(a0, b1, 0);
    BAR();
    LDA(1, 1, 1, a1);
    STAGE_HT(1, 3, T + 3);
    BAR();
    MM(a1, b1, 1);
    VMW(); BAR();
  }

  const int zi = n0 >> 10;
  const float* bias = (zi == 0) ? bq : (zi == 1) ? bk : bv;
  const int b = m0 >> 10;
  const int lbase = (m0 & 1023) + wr * 128;

  if (zi < 2) {
    unsigned short* op = ((zi == 0) ? Q : K);
#pragma unroll
    for (int n = 0; n < 4; ++n) {
      const int col = (n0 & 1023) + wc * 64 + n * 16 + lr;
      const int h = col >> 7, d = col & 127;
      const float bs = bias[col];
      unsigned short* hp = op + ((size_t)b * 8 + h) * 131072 + d;
#pragma unroll
      for (int m = 0; m < 8; ++m)
#pragma unroll
        for (int ii = 0; ii < 4; ++ii) {
          int l = lbase + m * 16 + lg * 4 + ii;
          hp[(size_t)l * 128] = f2bf(acc[m][n][ii] + bs);
        }
    }
  } else {
#pragma unroll
    for (int n = 0; n < 4; ++n) {
      const int col = (n0 & 1023) + wc * 64 + n * 16 + lr;
      const int h = col >> 7, d = col & 127;
      const float bs = bias[col];
      unsigned short* hp = Vt + ((size_t)b * 8 + h) * 131072 + (size_t)d * 1024;
#pragma unroll
      for (int m = 0; m < 8; ++m) {
        int l = lbase + m * 16 + lg * 4;
        ushort4 u = {f2bf(acc[m][n][0] + bs), f2bf(acc[m][n][1] + bs),
                     f2bf(acc[m][n][2] + bs), f2bf(acc[m][n][3] + bs)};
        *reinterpret_cast<ushort4*>(&hp[l]) = u;
      }
    }
  }
#undef STAGE_HT
}

// ============ Kernel C: out projection — 256^2 / BK64, 8-phase ============
__global__ __launch_bounds__(512, 2) void out_gemm8(
    const unsigned short* __restrict__ Wo, const unsigned short* __restrict__ O,
    const float* __restrict__ bo, float* __restrict__ out)
{
  __shared__ __align__(16) unsigned short lds[2][4][8192];

  const int tid = threadIdx.x;
  const int wave = tid >> 6, lane = tid & 63;
  const int lr = lane & 15, lg = lane >> 4;
  const int wr = wave >> 2, wc = wave & 3;

  const int b = blockIdx.y;
  const int bid = blockIdx.x;                  // 16 tiles per batch
  const int swz = (bid & 7) * 2 + (bid >> 3);  // bijective (16 % 8 == 0)
  const int mt = swz >> 2, nt = swz & 3;
  const int d0 = mt * 256, l0 = nt * 256;

  const unsigned short* Ag = Wo + (size_t)d0 * 1024;
  const unsigned short* Og = O + (size_t)b * 8 * 131072;

  const int srow = tid >> 2;
  const int schk = (tid & 3) * 8;

#define STAGE_HT(BUF, REG, TI)                                                 \
  {                                                                            \
    const int kt_ = ((TI) < 16 ? (TI) : 15) * 64 + (((REG)&1) * 32) + schk;    \
    if ((REG) < 2) {                                                           \
      _Pragma("unroll")                                                        \
      for (int j_ = 0; j_ < 2; ++j_)                                           \
        gload16(Ag + (size_t)(j_ * 128 + srow) * 1024 + kt_,                   \
                &lds[BUF][REG][j_ * 4096 + tid * 8]);                          \
    } else {                                                                   \
      const int h_ = kt_ >> 7, dk_ = kt_ & 127;                                \
      _Pragma("unroll")                                                        \
      for (int j_ = 0; j_ < 2; ++j_)                                           \
        gload16(Og + (size_t)h_ * 131072 +                                     \
                    (size_t)(l0 + j_ * 128 + srow) * 128 + dk_,                \
                &lds[BUF][REG][j_ * 4096 + tid * 8]);                          \
    }                                                                          \
  }

  f32x4 acc[8][4];
#pragma unroll
  for (int m = 0; m < 8; ++m)
#pragma unroll
    for (int n = 0; n < 4; ++n) acc[m][n] = (f32x4){0.f, 0.f, 0.f, 0.f};

  STAGE_HT(0, 2, 0); STAGE_HT(0, 0, 0); STAGE_HT(0, 3, 0); STAGE_HT(0, 1, 0);
  STAGE_HT(1, 2, 1); STAGE_HT(1, 0, 1); STAGE_HT(1, 3, 1);
  VMW();
  BAR();

  for (int it = 0; it < 8; ++it) {
    const int T = 2 * it;
    bf16x8 a0[4], a1[4], b0[4], b1[4];
    LDB(0, 0, b0); LDA(0, 0, 0, a0);
    STAGE_HT(1, 1, T + 1);
    BAR();
    MM(a0, b0, 0);
    BAR();
    LDA(0, 0, 1, a1);
    STAGE_HT(0, 2, T + 2);
    BAR();
    MM(a1, b0, 1);
    VMW(); BAR();
    LDB(0, 1, b1); LDA(0, 1, 0, a0);
    STAGE_HT(0, 0, T + 2);
    BAR();
    MM(a0, b1, 0);
    BAR();
    LDA(0, 1, 1, a1);
    STAGE_HT(0, 3, T + 2);
    BAR();
    MM(a1, b1, 1);
    VMW(); BAR();
    LDB(1, 0, b0); LDA(1, 0, 0, a0);
    STAGE_HT(0, 1, T + 2);
    BAR();
    MM(a0, b0, 0);
    BAR();
    LDA(1, 0, 1, a1);
    STAGE_HT(1, 2, T + 3);
    BAR();
    MM(a1, b0, 1);
    VMW(); BAR();
    LDB(1, 1, b1); LDA(1, 1, 0, a0);
    STAGE_HT(1, 0, T + 3);
    BAR();
    MM(a0, b1, 0);
    BAR();
    LDA(1, 1, 1, a1);
    STAGE_HT(1, 3, T + 3);
    BAR();
    MM(a1, b1, 1);
    VMW(); BAR();
  }

#pragma unroll
  for (int m = 0; m < 8; ++m) {
#pragma unroll
    for (int ii = 0; ii < 4; ++ii) {
      int dr = d0 + wr * 128 + m * 16 + lg * 4 + ii;
      float bs = bo[dr];
      float* orow = out + ((size_t)b * 1024 + dr) * 1024 + l0 + wc * 64 + lr;
#pragma unroll
      for (int n = 0; n < 4; ++n)
        orow[n * 16] = acc[m][n][ii] + bs;
    }
  }
#undef STAGE_HT
#undef LDA
#undef LDB
#undef MM
#undef BAR
#undef VMW
}

// ============ Kernel B: flash attention — QBLK=32/wave, KVBLK=64 ============
// grid (8 qtiles, 8 heads, 32 batch); 4 waves x 32 q-rows = 128 q/block.
// K frags + V frags read once per wave-tile, shared across both q-halves.
// LDS 77.5 KiB -> 2 blocks/CU. VGPR budget 256 (launch_bounds(256,2)).
__global__ __launch_bounds__(256, 2) void flash_attn(
    const unsigned short* __restrict__ Q, const unsigned short* __restrict__ Kb,
    const unsigned short* __restrict__ Vt, const int* __restrict__ mask,
    unsigned short* __restrict__ O)
{
  const int tid = threadIdx.x, wave = tid >> 6, lane = tid & 63;
  const int lr = lane & 15, lg = lane >> 4;
  const int qt = blockIdx.x, h = blockIdx.y, b = blockIdx.z;
  const size_t bh = (size_t)b * 8 + h;
  const unsigned short* Qp = Q + bh * 131072;
  const unsigned short* Kp = Kb + bh * 131072;
  const unsigned short* Vp = Vt + bh * 131072;
  unsigned short* Op = O + bh * 131072;
  const int q0 = qt * 128 + wave * 32;
  const float SC2 = 0.12751744f;        // (1/sqrt(128)) * log2(e)
  const float NEG2 = -1.442695e30f;     // -1e30 * log2(e)

  __shared__ __align__(16) unsigned short Kl[2][64 * 128];   // 2 x 16 KiB
  __shared__ __align__(16) unsigned short Vl[2][128 * 64];   // 2 x 16 KiB
  __shared__ __align__(16) unsigned short plds[4][16 * 76];  // 9.5 KiB
  __shared__ float pen[1024];                                // 4 KiB

  {
    const int4 mv = *reinterpret_cast<const int4*>(mask + b * 1024 + tid * 4);
    float4 pv;
    pv.x = mv.x ? NEG2 : 0.f; pv.y = mv.y ? NEG2 : 0.f;
    pv.z = mv.z ? NEG2 : 0.f; pv.w = mv.w ? NEG2 : 0.f;
    *reinterpret_cast<float4*>(&pen[tid * 4]) = pv;
  }

  unsigned short* myP = plds[wave];

  bf16x8 aq0[4], aq1[4];
#pragma unroll
  for (int c = 0; c < 4; ++c) {
    aq0[c] = *reinterpret_cast<const bf16x8*>(
        &Qp[(size_t)(q0 + lr) * 128 + c * 32 + lg * 8]);
    aq1[c] = *reinterpret_cast<const bf16x8*>(
        &Qp[(size_t)(q0 + 16 + lr) * 128 + c * 32 + lg * 8]);
  }

  // K: [64][128] rows 256B, byte ^= (row&7)<<4. V: [128][64] rows 128B, same XOR.
#define STAGE(bufi, ktv)                                                        \
  {                                                                             \
    _Pragma("unroll")                                                           \
    for (int i = 0; i < 4; ++i) {                                               \
      int krow = i * 16 + (tid >> 4);                                           \
      int kcb = ((tid & 15) * 16) ^ ((krow & 7) << 4);                          \
      gload16(Kp + (size_t)((ktv) + krow) * 128 + (kcb >> 1),                   \
              &Kl[bufi][i * 2048 + tid * 8]);                                   \
      int aoff = i * 4096 + tid * 16;                                           \
      int r_ = aoff >> 7;                                                       \
      int Lb = aoff ^ ((r_ & 7) << 4);                                          \
      gload16(Vp + (size_t)r_ * 1024 + (ktv) + ((Lb & 127) >> 1),               \
              &Vl[bufi][i * 2048 + tid * 8]);                                   \
    }                                                                           \
  }

  // per-q-half softmax + PV (sequential halves share one 16-row P buffer)
#define SMAXPV(S, MR, LRN, OA)                                                  \
  {                                                                             \
    float mx = fmaxf(                                                           \
        fmaxf(fmaxf(fmaxf(S[0][0], S[0][1]), fmaxf(S[0][2], S[0][3])),          \
              fmaxf(fmaxf(S[1][0], S[1][1]), fmaxf(S[1][2], S[1][3]))),         \
        fmaxf(fmaxf(fmaxf(S[2][0], S[2][1]), fmaxf(S[2][2], S[2][3])),          \
              fmaxf(fmaxf(S[3][0], S[3][1]), fmaxf(S[3][2], S[3][3]))));        \
    mx = fmaxf(mx, __shfl_xor(mx, 16));                                         \
    mx = fmaxf(mx, __shfl_xor(mx, 32));                                         \
    if (!__all(mx <= MR + 8.0f)) {                                              \
      float mnew = fmaxf(MR, mx);                                               \
      float scq = __builtin_amdgcn_exp2f(MR - mnew);                            \
      MR = mnew;                                                                \
      LRN *= scq;                                                               \
      _Pragma("unroll")                                                         \
      for (int i = 0; i < 4; ++i) {                                             \
        float sco = __shfl(scq, lg * 4 + i);                                    \
        _Pragma("unroll")                                                       \
        for (int dt = 0; dt < 8; ++dt) OA[dt][i] *= sco;                        \
      }                                                                         \
    }                                                                           \
    float p_[4][4];                                                             \
    float ls = 0.f;                                                             \
    _Pragma("unroll")                                                           \
    for (int n = 0; n < 4; ++n) {                                               \
      _Pragma("unroll")                                                         \
      for (int i = 0; i < 4; ++i)                                               \
        p_[n][i] = __builtin_amdgcn_exp2f(S[n][i] - MR);                        \
      ls += (p_[n][0] + p_[n][1]) + (p_[n][2] + p_[n][3]);                      \
    }                                                                           \
    ls += __shfl_xor(ls, 16);                                                   \
    ls += __shfl_xor(ls, 32);                                                   \
    LRN += ls;                                                                  \
    _Pragma("unroll")                                                           \
    for (int n = 0; n < 4; ++n)                                                 \
      _Pragma("unroll")                                                         \
      for (int t2 = 0; t2 < 2; ++t2) {                                          \
        unsigned int u_;                                                        \
        asm("v_cvt_pk_bf16_f32 %0, %1, %2"                                      \
            : "=v"(u_) : "v"(p_[n][2 * t2]), "v"(p_[n][2 * t2 + 1]));           \
        *reinterpret_cast<unsigned int*>(                                       \
            &myP[lr * 76 + n * 16 + lg * 4 + t2 * 2]) = u_;                     \
      }                                                                         \
    bf16x8 pa0_ = *reinterpret_cast<const bf16x8*>(&myP[lr * 76 + lg * 8]);     \
    bf16x8 pa1_ = *reinterpret_cast<const bf16x8*>(&myP[lr * 76 + 32 + lg * 8]);\
    __builtin_amdgcn_s_setprio(1);                                              \
    _Pragma("unroll")                                                           \
    for (int dt = 0; dt < 8; ++dt) {                                            \
      const int rr = dt * 16 + lr;                                              \
      const int rsw_ = (rr & 7) << 4;                                           \
      bf16x8 bv0 = *reinterpret_cast<const bf16x8*>(                            \
          &Vl[cur][(rr * 128 + ((lg * 16) ^ rsw_)) >> 1]);                      \
      bf16x8 bv1 = *reinterpret_cast<const bf16x8*>(                            \
          &Vl[cur][(rr * 128 + ((64 + lg * 16) ^ rsw_)) >> 1]);                 \
      OA[dt] = MFMA16(pa0_, bv0, OA[dt]);                                       \
      OA[dt] = MFMA16(pa1_, bv1, OA[dt]);                                       \
    }                                                                           \
    __builtin_amdgcn_s_setprio(0);                                              \
  }

  f32x4 oacc0[8], oacc1[8];
#pragma unroll
  for (int dt = 0; dt < 8; ++dt) {
    oacc0[dt] = (f32x4){0.f, 0.f, 0.f, 0.f};
    oacc1[dt] = (f32x4){0.f, 0.f, 0.f, 0.f};
  }
  float mrun0 = -3.0e38f, lrun0 = 0.f;
  float mrun1 = -3.0e38f, lrun1 = 0.f;

  STAGE(0, 0);
  __syncthreads();

  int cur = 0;
  for (int t = 0; t < 16; ++t) {
    const int kt = t * 64;
    if (t < 15) STAGE(cur ^ 1, kt + 64);

    // ---- S^T = K Q for both q-halves; K frags read once ----
    f32x4 s0[4], s1[4];
    __builtin_amdgcn_s_setprio(1);
#pragma unroll
    for (int n = 0; n < 4; ++n) {
      const int krow = n * 16 + lr;
      const int rsw = (krow & 7) << 4;
      f32x4 a0 = (f32x4){0.f, 0.f, 0.f, 0.f};
      f32x4 a1 = (f32x4){0.f, 0.f, 0.f, 0.f};
#pragma unroll
      for (int c = 0; c < 4; ++c) {
        bf16x8 bk = *reinterpret_cast<const bf16x8*>(
            &Kl[cur][krow * 128 + (((c * 64 + lg * 16) ^ rsw) >> 1)]);
        a0 = MFMA16(bk, aq0[c], a0);
        a1 = MFMA16(bk, aq1[c], a1);
      }
      s0[n] = a0;
      s1[n] = a1;
    }
    __builtin_amdgcn_s_setprio(0);

    // ---- scale + mask; pen frags shared across halves ----
#pragma unroll
    for (int n = 0; n < 4; ++n) {
      f32x4 pv = *reinterpret_cast<const f32x4*>(&pen[kt + n * 16 + lg * 4]);
#pragma unroll
      for (int i = 0; i < 4; ++i) {
        s0[n][i] = s0[n][i] * SC2 + pv[i];
        s1[n][i] = s1[n][i] * SC2 + pv[i];
      }
    }

    SMAXPV(s0, mrun0, lrun0, oacc0);
    SMAXPV(s1, mrun1, lrun1, oacc1);

    __syncthreads();
    cur ^= 1;
  }

  float linv0[4], linv1[4];
#pragma unroll
  for (int i = 0; i < 4; ++i) {
    linv0[i] = 1.0f / __shfl(lrun0, lg * 4 + i);
    linv1[i] = 1.0f / __shfl(lrun1, lg * 4 + i);
  }
#pragma unroll
  for (int dt = 0; dt < 8; ++dt)
#pragma unroll
    for (int i = 0; i < 4; ++i) {
      Op[(size_t)(q0 + lg * 4 + i) * 128 + dt * 16 + lr] =
          f2bf(oacc0[dt][i] * linv0[i]);
      Op[(size_t)(q0 + 16 + lg * 4 + i) * 128 + dt * 16 + lr] =
          f2bf(oacc1[dt][i] * linv1[i]);
    }
#undef STAGE
#undef SMAXPV
}

// ============ Fallback kernels (round-2, 192 MiB workspace) ============
__global__ __launch_bounds__(256) void qkv_proj_old(
    const float* __restrict__ x,
    const float* __restrict__ wq, const float* __restrict__ wk, const float* __restrict__ wv,
    const float* __restrict__ bq, const float* __restrict__ bk, const float* __restrict__ bv,
    unsigned short* __restrict__ Q, unsigned short* __restrict__ K, unsigned short* __restrict__ Vt)
{
  const int tid = threadIdx.x;
  const int wave = tid >> 6, lane = tid & 63;
  const int lr = lane & 15, lg = lane >> 4;
  const int wr = wave >> 1, wc = wave & 1;
  const int mt = blockIdx.x & 7, nt = blockIdx.x >> 3;
  const int b = blockIdx.y, z = blockIdx.z;
  const int l0 = mt * 128, i0 = nt * 128;
  const float* w    = (z == 0) ? wq : (z == 1) ? wk : wv;
  const float* bias = (z == 0) ? bq : (z == 1) ? bk : bv;
  unsigned short* outp = (z == 0) ? Q : (z == 1) ? K : Vt;

  __shared__ __align__(16) unsigned short lA[128 * 40];
  __shared__ __align__(16) unsigned short lB[128 * 40];

  f32x4 acc[4][4];
#pragma unroll
  for (int m = 0; m < 4; ++m)
#pragma unroll
    for (int n = 0; n < 4; ++n) acc[m][n] = (f32x4){0.f, 0.f, 0.f, 0.f};

  const int ad = tid >> 3, aj = tid & 7;
  const int br = tid >> 1, bh2 = tid & 1;

  for (int k0 = 0; k0 < 1024; k0 += 32) {
    const float* xp = x + ((size_t)b * 1024 + k0 + ad) * 1024 + l0;
#pragma unroll
    for (int rep = 0; rep < 4; ++rep) {
      float4 v = *reinterpret_cast<const float4*>(xp + aj * 4 + rep * 32);
      int lb = aj * 4 + rep * 32;
      lA[(lb + 0) * 40 + ad] = f2bf(v.x);
      lA[(lb + 1) * 40 + ad] = f2bf(v.y);
      lA[(lb + 2) * 40 + ad] = f2bf(v.z);
      lA[(lb + 3) * 40 + ad] = f2bf(v.w);
    }
    const float* wp = w + (size_t)(i0 + br) * 1024 + k0 + bh2 * 16;
#pragma unroll
    for (int rep = 0; rep < 4; ++rep) {
      float4 v = *reinterpret_cast<const float4*>(wp + rep * 4);
      int cb = br * 40 + bh2 * 16 + rep * 4;
      lB[cb + 0] = f2bf(v.x); lB[cb + 1] = f2bf(v.y);
      lB[cb + 2] = f2bf(v.z); lB[cb + 3] = f2bf(v.w);
    }
    __syncthreads();
    bf16x8 af[4], bfr[4];
#pragma unroll
    for (int m = 0; m < 4; ++m)
      af[m] = *reinterpret_cast<const bf16x8*>(&lA[(wr * 64 + m * 16 + lr) * 40 + lg * 8]);
#pragma unroll
    for (int n = 0; n < 4; ++n)
      bfr[n] = *reinterpret_cast<const bf16x8*>(&lB[(wc * 64 + n * 16 + lr) * 40 + lg * 8]);
#pragma unroll
    for (int m = 0; m < 4; ++m)
#pragma unroll
      for (int n = 0; n < 4; ++n)
        acc[m][n] = MFMA16(af[m], bfr[n], acc[m][n]);
    __syncthreads();
  }
#pragma unroll
  for (int n = 0; n < 4; ++n) {
    int col = i0 + wc * 64 + n * 16 + lr;
    float bs = bias[col];
    int h = col >> 7, d = col & 127;
#pragma unroll
    for (int m = 0; m < 4; ++m) {
#pragma unroll
      for (int ii = 0; ii < 4; ++ii) {
        int row = l0 + wr * 64 + m * 16 + lg * 4 + ii;
        unsigned short val = f2bf(acc[m][n][ii] + bs);
        if (z < 2)
          outp[(((size_t)b * 8 + h) * 1024 + row) * 128 + d] = val;
        else
          outp[(((size_t)b * 8 + h) * 128 + d) * 1024 + row] = val;
      }
    }
  }
}

__global__ __launch_bounds__(256) void out_proj_old(
    const unsigned short* __restrict__ Obuf, const float* __restrict__ wo,
    const float* __restrict__ bo, float* __restrict__ out)
{
  const int tid = threadIdx.x, wave = tid >> 6, lane = tid & 63;
  const int lr = lane & 15, lg = lane >> 4;
  const int wr = wave >> 1, wc = wave & 1;
  const int mt = blockIdx.x & 7, nt = blockIdx.x >> 3;
  const int b = blockIdx.y;
  const int d0 = mt * 128, l0 = nt * 128;

  __shared__ __align__(16) unsigned short lA[128 * 40];
  __shared__ __align__(16) unsigned short lB[128 * 40];

  f32x4 acc[4][4];
#pragma unroll
  for (int m = 0; m < 4; ++m)
#pragma unroll
    for (int n = 0; n < 4; ++n) acc[m][n] = (f32x4){0.f, 0.f, 0.f, 0.f};

  const int ar = tid >> 1, ah = tid & 1;

  for (int k0 = 0; k0 < 1024; k0 += 32) {
    const float* wp = wo + (size_t)(d0 + ar) * 1024 + k0 + ah * 16;
#pragma unroll
    for (int rep = 0; rep < 4; ++rep) {
      float4 v = *reinterpret_cast<const float4*>(wp + rep * 4);
      int cb = ar * 40 + ah * 16 + rep * 4;
      lA[cb + 0] = f2bf(v.x); lA[cb + 1] = f2bf(v.y);
      lA[cb + 2] = f2bf(v.z); lA[cb + 3] = f2bf(v.w);
    }
    {
      int head = k0 >> 7, dk = (k0 & 127) + ah * 16;
      const unsigned short* op =
          Obuf + (((size_t)b * 8 + head) * 1024 + l0 + ar) * 128 + dk;
#pragma unroll
      for (int rep = 0; rep < 2; ++rep) {
        bf16x8 v = *reinterpret_cast<const bf16x8*>(op + rep * 8);
        *reinterpret_cast<bf16x8*>(&lB[ar * 40 + ah * 16 + rep * 8]) = v;
      }
    }
    __syncthreads();
    bf16x8 af[4], bfr[4];
#pragma unroll
    for (int m = 0; m < 4; ++m)
      af[m] = *reinterpret_cast<const bf16x8*>(&lA[(wr * 64 + m * 16 + lr) * 40 + lg * 8]);
#pragma unroll
    for (int n = 0; n < 4; ++n)
      bfr[n] = *reinterpret_cast<const bf16x8*>(&lB[(wc * 64 + n * 16 + lr) * 40 + lg * 8]);
#pragma unroll
    for (int m = 0; m < 4; ++m)
#pragma unroll
      for (int n = 0; n < 4; ++n)
        acc[m][n] = MFMA16(af[m], bfr[n], acc[m][n]);
    __syncthreads();
  }
#pragma unroll
  for (int m = 0; m < 4; ++m) {
#pragma unroll
    for (int ii = 0; ii < 4; ++ii) {
      int dr = d0 + wr * 64 + m * 16 + lg * 4 + ii;
      float bs = bo[dr];
      float* orow = out + ((size_t)b * 1024 + dr) * 1024 + l0 + wc * 64 + lr;
#pragma unroll
      for (int n = 0; n < 4; ++n)
        orow[n * 16] = acc[m][n][ii] + bs;
    }
  }
}

extern "C" void kernel_launch(void* const* d_in, const int* in_sizes, int n_in,
                              void* d_out, int out_size, void* d_ws, size_t ws_size,
                              hipStream_t stream) {
  const float* x  = (const float*)d_in[0];
  const int* mask = (const int*)d_in[1];
  const float* wq = (const float*)d_in[2];
  const float* bq = (const float*)d_in[3];
  const float* wk = (const float*)d_in[4];
  const float* bk = (const float*)d_in[5];
  const float* wv = (const float*)d_in[6];
  const float* bv = (const float*)d_in[7];
  const float* wo = (const float*)d_in[8];
  const float* bo = (const float*)d_in[9];
  float* out = (float*)d_out;

  const size_t MB64 = (size_t)64 << 20;
  const size_t NEED = (size_t)264 << 20;

  if (ws_size >= NEED) {
    unsigned short* xT   = (unsigned short*)d_ws;
    unsigned short* Q    = (unsigned short*)((char*)d_ws + MB64);
    unsigned short* K    = (unsigned short*)((char*)d_ws + 2 * MB64);
    unsigned short* Vt   = (unsigned short*)((char*)d_ws + 3 * MB64);
    unsigned short* Wqkv = (unsigned short*)((char*)d_ws + 4 * MB64);
    unsigned short* Wo   = Wqkv + (size_t)3 * 1048576;

    x_transpose<<<dim3(16, 16, 32), 256, 0, stream>>>(x, xT);
    w_convert<<<dim3(1024, 4), 256, 0, stream>>>(wq, wk, wv, wo, Wqkv, Wo);
    qkv_gemm8<<<dim3(1536), 512, 0, stream>>>(xT, Wqkv, bq, bk, bv, Q, K, Vt);
    flash_attn<<<dim3(8, 8, 32), 256, 0, stream>>>(Q, K, Vt, mask, Q);
    out_gemm8<<<dim3(16, 32), 512, 0, stream>>>(Wo, Q, bo, out);
  } else {
    unsigned short* Q  = (unsigned short*)d_ws;
    unsigned short* K  = Q + (size_t)33554432;
    unsigned short* Vt = K + (size_t)33554432;
    qkv_proj_old<<<dim3(64, 32, 3), 256, 0, stream>>>(x, wq, wk, wv, bq, bk, bv, Q, K, Vt);
    flash_attn<<<dim3(8, 8, 32), 256, 0, stream>>>(Q, K, Vt, mask, Q);
    out_proj_old<<<dim3(64, 32), 256, 0, stream>>>(Q, wo, bo, out);
  }
}